// Round 8
// baseline (2375.833 us; speedup 1.0000x reference)
//
#include <hip/hip_runtime.h>

typedef unsigned short ushort_t;
using short8  = __attribute__((ext_vector_type(8))) short;
using short4v = __attribute__((ext_vector_type(4))) short;
using f32x4   = __attribute__((ext_vector_type(4))) float;

#define DI __device__ __forceinline__

DI ushort_t f2bf(float f){
  union { float f; unsigned u; } v; v.f = f;
  unsigned u = v.u;
  return (ushort_t)((u + 0x7FFFu + ((u >> 16) & 1u)) >> 16);
}
DI float bf2f(ushort_t u){
  union { unsigned u; float f; } v; v.u = ((unsigned)u) << 16;
  return v.f;
}
DI unsigned pack2(float lo, float hi){
  return ((unsigned)f2bf(hi) << 16) | (unsigned)f2bf(lo);
}
DI float unpk_lo(unsigned u){ return bf2f((ushort_t)(u & 0xFFFFu)); }
DI float unpk_hi(unsigned u){ return bf2f((ushort_t)(u >> 16)); }

DI f32x4 MFMA(short8 a, short8 b, f32x4 c){
  return __builtin_amdgcn_mfma_f32_16x16x32_bf16(a, b, c, 0, 0, 0);
}

// swizzled LDS bf16 tile addressing; row stride 256 elems (512B)
DI int swzi(int row, int col){
  int byte = (row << 9) + (col << 1);
  byte ^= (row & 7) << 4;
  return byte >> 1;
}
DI short8 ldsA(const ushort_t* buf, int row, int k0){
  return *(const short8*)(buf + swzi(row, k0));
}
DI short8 ldG(const ushort_t* p){ return *(const short8*)p; }

// fallback B-fragment builders from f32 global (used when ws too small)
DI short8 loadWT(const float* __restrict__ W, int n, int k0){
  short8 s;
#pragma unroll
  for (int j = 0; j < 8; j++) s[j] = (short)f2bf(W[(k0 + j) * 256 + n]);
  return s;
}
DI short8 loadWT16(const float* __restrict__ W, int n, int k0){
  short8 s;
#pragma unroll
  for (int j = 0; j < 8; j++){
    int k = k0 + j;
    s[j] = (short)((k < 16) ? f2bf(W[k * 256 + n]) : 0);
  }
  return s;
}
DI short8 loadWrow(const float* __restrict__ W, int n, int k0){
  short8 s;
#pragma unroll
  for (int j = 0; j < 8; j++) s[j] = (short)f2bf(W[n * 256 + k0 + j]);
  return s;
}

// d_ws layout (ushort indices)
#define WS_NEWT  0        // [256][32]  neW^T, K padded 16->32
#define WS_W1AT1 8192     // [256][256] g1W1[0:256]^T
#define WS_W1BT1 73728    // [256][256] g1W1[256:512]^T
#define WS_W2T1  139264   // [256][256] g1W2^T
#define WS_W1AT2 204800
#define WS_W1BT2 270336
#define WS_W2T2  335872
#define WS_PQWT  401408   // [256][256] pqW^T
#define WS_PKWP  466944   // [256][256] pkW plain copy (acts as B^T for r-GEMM)
#define WS_TOTAL 532480
#define WS_BYTES (WS_TOTAL * 2)

__global__ void prep_weights(
    const float* __restrict__ neW, const float* __restrict__ g1W1,
    const float* __restrict__ g1W2, const float* __restrict__ g2W1,
    const float* __restrict__ g2W2, const float* __restrict__ pqW,
    const float* __restrict__ pkW, ushort_t* __restrict__ ws)
{
  int i = blockIdx.x * 256 + threadIdx.x;
  if (i >= WS_TOTAL) return;
  float v;
  if (i < 8192){
    int n = i >> 5, k = i & 31;
    v = (k < 16) ? neW[k * 256 + n] : 0.0f;
  } else {
    int j = i - 8192;
    int region = j >> 16;
    int idx = j & 65535;
    int n = idx >> 8, k = idx & 255;
    switch (region){
      case 0: v = g1W1[k * 256 + n]; break;
      case 1: v = g1W1[(256 + k) * 256 + n]; break;
      case 2: v = g1W2[k * 256 + n]; break;
      case 3: v = g2W1[k * 256 + n]; break;
      case 4: v = g2W1[(256 + k) * 256 + n]; break;
      case 5: v = g2W2[k * 256 + n]; break;
      case 6: v = pqW[k * 256 + n]; break;
      default: v = pkW[idx]; break;   // plain row-major copy
    }
  }
  ws[i] = f2bf(v);
}

// 1 workgroup = 4 batches = 80 rows. 4 waves; wave owns a 64-col N-slice.
// Residual h kept as packed bf16 in registers (hpk) -> VGPR <= 168 -> 3 blocks/CU.
// Output f32: [oh B*8 | c1 B*10 | c2 B*10 | pl B*20].
template<bool PREPPED>
__global__ __launch_bounds__(256, 3) void fused_graphnet(
    const float* __restrict__ nf, const int* __restrict__ nn_c,
    const float* __restrict__ neW, const float* __restrict__ neb,
    const float* __restrict__ g1W1, const float* __restrict__ g1b1,
    const float* __restrict__ g1W2, const float* __restrict__ g1b2,
    const float* __restrict__ g2W1, const float* __restrict__ g2b1,
    const float* __restrict__ g2W2, const float* __restrict__ g2b2,
    const float* __restrict__ n1g, const float* __restrict__ n1b,
    const float* __restrict__ n2g, const float* __restrict__ n2b,
    const float* __restrict__ ohW, const float* __restrict__ ohb,
    const float* __restrict__ c1W, const float* __restrict__ c1b,
    const float* __restrict__ c2W, const float* __restrict__ c2b,
    const float* __restrict__ pqW, const float* __restrict__ pqb,
    const float* __restrict__ pkW, const float* __restrict__ pkb,
    const ushort_t* __restrict__ ws, float* __restrict__ out,
    int out_n, int Bv)
{
  __shared__ __align__(16) ushort_t hbuf[80 * 256];  // 40KB swizzled bf16
  __shared__ __align__(16) ushort_t smallA[8 * 256]; // 4KB: msg/g rows 0..3, q rows 4..7
  __shared__ float pbf[4 * 256];                     // pb then r
  __shared__ float rowstats[4][80][2];
  __shared__ float qdot[4];
  __shared__ int   cntS[4];
  __shared__ float dinvS[4];

  const int b0 = blockIdx.x * 4;
  const int tid = threadIdx.x;
  const int wave = tid >> 6, lane = tid & 63;
  const int lg = lane >> 4, lc = lane & 15;
  const int n0 = wave * 64;

  const int Bout = out_n / 48;
  const int off_c1 = 8 * Bout;
  const int off_c2 = 18 * Bout;
  const int off_pl = 28 * Bout;

  if (tid < 4){
    int bi = b0 + tid; if (bi >= Bv) bi = Bv - 1;
    int c = nn_c[bi];
    c = c < 0 ? 0 : (c > 20 ? 20 : c);
    cntS[tid] = c;
    dinvS[tid] = 1.0f / (float)(c < 1 ? 1 : c);
  }

  // zero K-pad cols 16..31 (rows 0..79) and stage nf cols 0..15 (disjoint)
  for (int i = tid; i < 80 * 4; i += 256){   // short4 zero writes
    int row = i >> 2, c0 = 16 + (i & 3) * 4;
    *(short4v*)(hbuf + swzi(row, c0)) = (short4v){0, 0, 0, 0};
  }
  for (int i = tid; i < 80 * 16; i += 256){
    int row = i >> 4, k = i & 15;
    int gr = b0 * 20 + row; if (gr >= Bv * 20) gr = Bv * 20 - 1;
    hbuf[swzi(row, k)] = f2bf(nf[gr * 16 + k]);
  }
  __syncthreads();

  const f32x4 zero4 = {0.0f, 0.0f, 0.0f, 0.0f};

  // residual h as packed bf16: hpk[mt][nt][rp] holds rows (lg*4+2rp, lg*4+2rp+1)
  unsigned hpk[5][4][2];

  // GEMM0: h0 = nf @ neW + neb (single K-step of 32); pack + store
  {
    f32x4 acc[5][4];
#pragma unroll
    for (int mt = 0; mt < 5; mt++){
      short8 a = ldsA(hbuf, mt * 16 + lc, lg * 8);
#pragma unroll
      for (int nt = 0; nt < 4; nt++){
        int n = n0 + nt * 16 + lc;
        short8 bv;
        if constexpr (PREPPED) bv = ldG(ws + WS_NEWT + n * 32 + lg * 8);
        else bv = loadWT16(neW, n, lg * 8);
        acc[mt][nt] = MFMA(a, bv, zero4);
      }
    }
#pragma unroll
    for (int nt = 0; nt < 4; nt++){
      float bb = neb[n0 + nt * 16 + lc];
#pragma unroll
      for (int mt = 0; mt < 5; mt++)
#pragma unroll
        for (int r = 0; r < 4; r++) acc[mt][nt][r] += bb;
    }
    __syncthreads();  // GEMM0 LDS reads done before overwrite
#pragma unroll
    for (int mt = 0; mt < 5; mt++)
#pragma unroll
      for (int nt = 0; nt < 4; nt++){
        hpk[mt][nt][0] = pack2(acc[mt][nt][0], acc[mt][nt][1]);
        hpk[mt][nt][1] = pack2(acc[mt][nt][2], acc[mt][nt][3]);
#pragma unroll
        for (int r = 0; r < 4; r++)
          hbuf[swzi(mt * 16 + lg * 4 + r, n0 + nt * 16 + lc)] = f2bf(acc[mt][nt][r]);
      }
  }
  __syncthreads();

  for (int rd = 0; rd < 2; rd++){
    const int w1at = (rd == 0) ? WS_W1AT1 : WS_W1AT2;
    const int w1bt = (rd == 0) ? WS_W1BT1 : WS_W1BT2;
    const int w2t  = (rd == 0) ? WS_W2T1  : WS_W2T2;
    const float* W1 = (rd == 0) ? g1W1 : g2W1;
    const float* W2 = (rd == 0) ? g1W2 : g2W2;
    const float* b1p = (rd == 0) ? g1b1 : g2b1;
    const float* b2p = (rd == 0) ? g1b2 : g2b2;
    const float* ngp = (rd == 0) ? n1g : n2g;
    const float* nbp = (rd == 0) ? n1b : n2b;

    // masked mean -> smallA rows 0..3 (bf16 msg); thread: batch tid>>6, cols 4*(tid&63)
    {
      int b = tid >> 6;
      int c0 = (tid & 63) * 4;
      int c = cntS[b];
      float s0 = 0, s1 = 0, s2 = 0, s3 = 0;
      for (int r = 0; r < c; r++){
        short4v v = *(const short4v*)(hbuf + swzi(b * 20 + r, c0));
        s0 += bf2f((ushort_t)v[0]); s1 += bf2f((ushort_t)v[1]);
        s2 += bf2f((ushort_t)v[2]); s3 += bf2f((ushort_t)v[3]);
      }
      float di = dinvS[b];
      short4v o;
      o[0] = (short)f2bf(s0 * di); o[1] = (short)f2bf(s1 * di);
      o[2] = (short)f2bf(s2 * di); o[3] = (short)f2bf(s3 * di);
      *(short4v*)(smallA + swzi(b, c0)) = o;
    }
    __syncthreads();

    // pb = msg @ W1b + b1 (batch rows 0..3)
    {
      f32x4 acc[4];
#pragma unroll
      for (int nt = 0; nt < 4; nt++) acc[nt] = zero4;
#pragma unroll
      for (int kk = 0; kk < 8; kk++){
        short8 a = ldsA(smallA, lc & 3, kk * 32 + lg * 8);
#pragma unroll
        for (int nt = 0; nt < 4; nt++){
          int n = n0 + nt * 16 + lc;
          short8 bv;
          if constexpr (PREPPED) bv = ldG(ws + w1bt + n * 256 + kk * 32 + lg * 8);
          else bv = loadWT(W1 + 256 * 256, n, kk * 32 + lg * 8);
          acc[nt] = MFMA(a, bv, acc[nt]);
        }
      }
      if (lg == 0){
#pragma unroll
        for (int nt = 0; nt < 4; nt++)
#pragma unroll
          for (int r = 0; r < 4; r++){
            int col = n0 + nt * 16 + lc;
            pbf[r * 256 + col] = acc[nt][r] + b1p[col];
          }
      }
    }

    // G1: tacc = h @ W1a
    f32x4 tacc[5][4];
#pragma unroll
    for (int mt = 0; mt < 5; mt++)
#pragma unroll
      for (int nt = 0; nt < 4; nt++) tacc[mt][nt] = zero4;
#pragma unroll
    for (int kk = 0; kk < 8; kk++){
#pragma unroll
      for (int mt = 0; mt < 5; mt++){
        short8 a = ldsA(hbuf, mt * 16 + lc, kk * 32 + lg * 8);
#pragma unroll
        for (int nt = 0; nt < 4; nt++){
          int n = n0 + nt * 16 + lc;
          short8 bv;
          if constexpr (PREPPED) bv = ldG(ws + w1at + n * 256 + kk * 32 + lg * 8);
          else bv = loadWT(W1, n, kk * 32 + lg * 8);
          tacc[mt][nt] = MFMA(a, bv, tacc[mt][nt]);
        }
      }
    }
    __syncthreads();  // all h reads + pbf writes complete

    // t1 = relu(tacc + pb[batch]) -> hbuf
#pragma unroll
    for (int mt = 0; mt < 5; mt++)
#pragma unroll
      for (int nt = 0; nt < 4; nt++)
#pragma unroll
        for (int r = 0; r < 4; r++){
          int row = mt * 16 + lg * 4 + r;
          int col = n0 + nt * 16 + lc;
          float v = tacc[mt][nt][r] + pbf[(row / 20) * 256 + col];
          hbuf[swzi(row, col)] = f2bf(fmaxf(v, 0.0f));
        }
    __syncthreads();

    // tacc = t1 @ W2 (fresh acc), then v = residual(hpk) + tacc + b2 -> LN
#pragma unroll
    for (int mt = 0; mt < 5; mt++)
#pragma unroll
      for (int nt = 0; nt < 4; nt++) tacc[mt][nt] = zero4;
#pragma unroll
    for (int kk = 0; kk < 8; kk++){
#pragma unroll
      for (int mt = 0; mt < 5; mt++){
        short8 a = ldsA(hbuf, mt * 16 + lc, kk * 32 + lg * 8);
#pragma unroll
        for (int nt = 0; nt < 4; nt++){
          int n = n0 + nt * 16 + lc;
          short8 bv;
          if constexpr (PREPPED) bv = ldG(ws + w2t + n * 256 + kk * 32 + lg * 8);
          else bv = loadWT(W2, n, kk * 32 + lg * 8);
          tacc[mt][nt] = MFMA(a, bv, tacc[mt][nt]);
        }
      }
    }
    // add residual + b2
#pragma unroll
    for (int nt = 0; nt < 4; nt++){
      float b2s = b2p[n0 + nt * 16 + lc];
#pragma unroll
      for (int mt = 0; mt < 5; mt++){
        tacc[mt][nt][0] += unpk_lo(hpk[mt][nt][0]) + b2s;
        tacc[mt][nt][1] += unpk_hi(hpk[mt][nt][0]) + b2s;
        tacc[mt][nt][2] += unpk_lo(hpk[mt][nt][1]) + b2s;
        tacc[mt][nt][3] += unpk_hi(hpk[mt][nt][1]) + b2s;
      }
    }

    // LayerNorm over 256 cols, then *mask; pack result back into hpk + hbuf
    {
#pragma unroll
      for (int mt = 0; mt < 5; mt++)
#pragma unroll
        for (int r = 0; r < 4; r++){
          int row = mt * 16 + lg * 4 + r;
          float s1 = 0, s2 = 0;
#pragma unroll
          for (int nt = 0; nt < 4; nt++){ float v = tacc[mt][nt][r]; s1 += v; s2 += v * v; }
#pragma unroll
          for (int d = 1; d < 16; d <<= 1){ s1 += __shfl_xor(s1, d, 64); s2 += __shfl_xor(s2, d, 64); }
          if (lc == 0){ rowstats[wave][row][0] = s1; rowstats[wave][row][1] = s2; }
        }
      __syncthreads();  // stats published; all G2 hbuf reads done
      float ngv[4], nbv[4];
#pragma unroll
      for (int nt = 0; nt < 4; nt++){
        ngv[nt] = ngp[n0 + nt * 16 + lc];
        nbv[nt] = nbp[n0 + nt * 16 + lc];
      }
#pragma unroll
      for (int mt = 0; mt < 5; mt++){
#pragma unroll
        for (int r = 0; r < 4; r++){
          int row = mt * 16 + lg * 4 + r;
          float t1s = rowstats[0][row][0] + rowstats[1][row][0] + rowstats[2][row][0] + rowstats[3][row][0];
          float t2s = rowstats[0][row][1] + rowstats[1][row][1] + rowstats[2][row][1] + rowstats[3][row][1];
          float mean = t1s * (1.0f / 256.0f);
          float var  = t2s * (1.0f / 256.0f) - mean * mean;
          float rstd = rsqrtf(fmaxf(var, 0.0f) + 1e-5f);
          int bb = row / 20;
          float mf = ((row - bb * 20) < cntS[bb]) ? 1.0f : 0.0f;
#pragma unroll
          for (int nt = 0; nt < 4; nt++){
            int col = n0 + nt * 16 + lc;
            float v = ((tacc[mt][nt][r] - mean) * rstd * ngv[nt] + nbv[nt]) * mf;
            tacc[mt][nt][r] = v;
            hbuf[swzi(row, col)] = f2bf(v);
          }
        }
#pragma unroll
        for (int nt = 0; nt < 4; nt++){
          hpk[mt][nt][0] = pack2(tacc[mt][nt][0], tacc[mt][nt][1]);
          hpk[mt][nt][1] = pack2(tacc[mt][nt][2], tacc[mt][nt][3]);
        }
      }
    }
    __syncthreads();
  }

  // g = masked mean -> smallA rows 0..3 (bf16)
  {
    int b = tid >> 6;
    int c0 = (tid & 63) * 4;
    int c = cntS[b];
    float s0 = 0, s1 = 0, s2 = 0, s3 = 0;
    for (int r = 0; r < c; r++){
      short4v v = *(const short4v*)(hbuf + swzi(b * 20 + r, c0));
      s0 += bf2f((ushort_t)v[0]); s1 += bf2f((ushort_t)v[1]);
      s2 += bf2f((ushort_t)v[2]); s3 += bf2f((ushort_t)v[3]);
    }
    float di = dinvS[b];
    short4v o;
    o[0] = (short)f2bf(s0 * di); o[1] = (short)f2bf(s1 * di);
    o[2] = (short)f2bf(s2 * di); o[3] = (short)f2bf(s3 * di);
    *(short4v*)(smallA + swzi(b, c0)) = o;
  }
  __syncthreads();

  // q = g @ pqW + pqb -> smallA rows 4..7 (disjoint rows; no barrier inside)
  {
    f32x4 qacc[4];
#pragma unroll
    for (int nt = 0; nt < 4; nt++) qacc[nt] = zero4;
#pragma unroll
    for (int kk = 0; kk < 8; kk++){
      short8 a = ldsA(smallA, lc & 3, kk * 32 + lg * 8);
#pragma unroll
      for (int nt = 0; nt < 4; nt++){
        int n = n0 + nt * 16 + lc;
        short8 bv;
        if constexpr (PREPPED) bv = ldG(ws + WS_PQWT + n * 256 + kk * 32 + lg * 8);
        else bv = loadWT(pqW, n, kk * 32 + lg * 8);
        qacc[nt] = MFMA(a, bv, qacc[nt]);
      }
    }
    if (lg == 0){
#pragma unroll
      for (int nt = 0; nt < 4; nt++)
#pragma unroll
        for (int r = 0; r < 4; r++){
          int col = n0 + nt * 16 + lc;
          smallA[swzi(4 + r, col)] = f2bf(qacc[nt][r] + pqb[col]);
        }
    }
  }
  __syncthreads();

  // qdot[b] = q[b].pkb (wave w = batch w; q bf16 from smallA rows 4..7)
  {
    short4v qv = *(const short4v*)(smallA + swzi(4 + wave, lane * 4));
    float p = bf2f((ushort_t)qv[0]) * pkb[lane * 4 + 0]
            + bf2f((ushort_t)qv[1]) * pkb[lane * 4 + 1]
            + bf2f((ushort_t)qv[2]) * pkb[lane * 4 + 2]
            + bf2f((ushort_t)qv[3]) * pkb[lane * 4 + 3];
#pragma unroll
    for (int d = 1; d < 64; d <<= 1) p += __shfl_xor(p, d, 64);
    if (lane == 0) qdot[wave] = p;
  }

  // r[b][n] = sum_k q[b][k]*pkW[n][k] -> pbf
  {
    f32x4 racc[4];
#pragma unroll
    for (int nt = 0; nt < 4; nt++) racc[nt] = zero4;
#pragma unroll
    for (int kk = 0; kk < 8; kk++){
      short8 a = ldsA(smallA, 4 + (lc & 3), kk * 32 + lg * 8);
#pragma unroll
      for (int nt = 0; nt < 4; nt++){
        int n = n0 + nt * 16 + lc;
        short8 bv;
        if constexpr (PREPPED) bv = ldG(ws + WS_PKWP + n * 256 + kk * 32 + lg * 8);
        else bv = loadWrow(pkW, n, kk * 32 + lg * 8);
        racc[nt] = MFMA(a, bv, racc[nt]);
      }
    }
    if (lg == 0){
#pragma unroll
      for (int nt = 0; nt < 4; nt++)
#pragma unroll
        for (int r = 0; r < 4; r++)
          pbf[r * 256 + (n0 + nt * 16 + lc)] = racc[nt][r];
    }
  }
  __syncthreads();

  // pl[b,n] = h[row].r[b] + qdot[b] (masked -> exactly -1e9); wave w = batch w
  {
    const int b = wave;
    if (b0 + b < Bv){
      int cb = cntS[b];
      float qd = qdot[b];
      for (int rr = 0; rr < 20; rr++){
        int row = b * 20 + rr;
        short4v hv = *(const short4v*)(hbuf + swzi(row, lane * 4));
        const float* rp = pbf + b * 256 + lane * 4;
        float p = bf2f((ushort_t)hv[0]) * rp[0] + bf2f((ushort_t)hv[1]) * rp[1]
                + bf2f((ushort_t)hv[2]) * rp[2] + bf2f((ushort_t)hv[3]) * rp[3];
#pragma unroll
        for (int d = 1; d < 64; d <<= 1) p += __shfl_xor(p, d, 64);
        if (lane == 0){
          float v = (rr < cb) ? (p + qd) : -1e9f;
          out[off_pl + (b0 + b) * 20 + rr] = v;
        }
      }
    }
  }

  // heads (wave w = batch w): oh [B,8]@0, c1 [B,10]@off_c1, c2 [B,10]@off_c2
  {
    const int b = wave;
    if (b0 + b < Bv){
      short4v gv = *(const short4v*)(smallA + swzi(b, lane * 4));
      float g0 = bf2f((ushort_t)gv[0]), g1 = bf2f((ushort_t)gv[1]);
      float g2 = bf2f((ushort_t)gv[2]), g3 = bf2f((ushort_t)gv[3]);
#pragma unroll
      for (int o = 0; o < 28; o++){
        const float* W; const float* bias; int ncol, col, off;
        if (o < 8)      { W = ohW; bias = ohb; ncol = 8;  col = o;      off = 0; }
        else if (o < 18){ W = c1W; bias = c1b; ncol = 10; col = o - 8;  off = off_c1; }
        else            { W = c2W; bias = c2b; ncol = 10; col = o - 18; off = off_c2; }
        int k = lane * 4;
        float p = g0 * W[(k + 0) * ncol + col] + g1 * W[(k + 1) * ncol + col]
                + g2 * W[(k + 2) * ncol + col] + g3 * W[(k + 3) * ncol + col];
#pragma unroll
        for (int d = 1; d < 64; d <<= 1) p += __shfl_xor(p, d, 64);
        if (lane == 0) out[off + (b0 + b) * ncol + col] = p + bias[col];
      }
    }
  }
}

extern "C" void kernel_launch(void* const* d_in, const int* in_sizes, int n_in,
                              void* d_out, int out_size, void* d_ws, size_t ws_size,
                              hipStream_t stream)
{
  const float* nf   = (const float*)d_in[0];
  const int*   nn_c = (const int*)d_in[1];
  const float* neW  = (const float*)d_in[2];
  const float* neb  = (const float*)d_in[3];
  const float* g1W1 = (const float*)d_in[4];
  const float* g1b1 = (const float*)d_in[5];
  const float* g1W2 = (const float*)d_in[6];
  const float* g1b2 = (const float*)d_in[7];
  const float* g2W1 = (const float*)d_in[8];
  const float* g2b1 = (const float*)d_in[9];
  const float* g2W2 = (const float*)d_in[10];
  const float* g2b2 = (const float*)d_in[11];
  const float* n1g  = (const float*)d_in[12];
  const float* n1b  = (const float*)d_in[13];
  const float* n2g  = (const float*)d_in[14];
  const float* n2b  = (const float*)d_in[15];
  const float* ohW  = (const float*)d_in[16];
  const float* ohb  = (const float*)d_in[17];
  const float* c1W  = (const float*)d_in[18];
  const float* c1b  = (const float*)d_in[19];
  const float* c2W  = (const float*)d_in[20];
  const float* c2b  = (const float*)d_in[21];
  const float* pqW  = (const float*)d_in[22];
  const float* pqb  = (const float*)d_in[23];
  const float* pkW  = (const float*)d_in[24];
  const float* pkb  = (const float*)d_in[25];

  float* outp = (float*)d_out;
  ushort_t* ws = (ushort_t*)d_ws;
  int B = in_sizes[0] / 320;       // nf is [B,20,16]
  int grid = (B + 3) / 4;

  if (ws_size >= (size_t)WS_BYTES){
    prep_weights<<<(WS_TOTAL + 255) / 256, 256, 0, stream>>>(
        neW, g1W1, g1W2, g2W1, g2W2, pqW, pkW, ws);
    fused_graphnet<true><<<grid, 256, 0, stream>>>(
        nf, nn_c, neW, neb, g1W1, g1b1, g1W2, g1b2, g2W1, g2b1, g2W2, g2b2,
        n1g, n1b, n2g, n2b, ohW, ohb, c1W, c1b, c2W, c2b, pqW, pqb, pkW, pkb,
        ws, outp, out_size, B);
  } else {
    fused_graphnet<false><<<grid, 256, 0, stream>>>(
        nf, nn_c, neW, neb, g1W1, g1b1, g1W2, g1b2, g2W1, g2b1, g2W2, g2b2,
        n1g, n1b, n2g, n2b, ohW, ohb, c1W, c1b, c2W, c2b, pqW, pqb, pkW, pkb,
        ws, outp, out_size, B);
  }
}

// Round 9
// 1738.441 us; speedup vs baseline: 1.3666x; 1.3666x over previous
//
#include <hip/hip_runtime.h>

typedef unsigned char u8;
typedef unsigned int  u32;
using f32x4 = __attribute__((ext_vector_type(4))) float;

#define DI __device__ __forceinline__

// ---- fp8 e4m3 (OCP on gfx950) HW converts ----
DI u32 pk4f8(float a, float b, float c, float d){
  int w = __builtin_amdgcn_cvt_pk_fp8_f32(a, b, 0, false);
  w = __builtin_amdgcn_cvt_pk_fp8_f32(c, d, w, true);
  return (u32)w;
}
DI u8 enc1(float a){
  return (u8)(__builtin_amdgcn_cvt_pk_fp8_f32(a, a, 0, false) & 0xFF);
}
DI float dc0(u32 v){ return __builtin_amdgcn_cvt_f32_fp8((int)v, 0); }
DI float dc1(u32 v){ return __builtin_amdgcn_cvt_f32_fp8((int)v, 1); }
DI float dc2(u32 v){ return __builtin_amdgcn_cvt_f32_fp8((int)v, 2); }
DI float dc3(u32 v){ return __builtin_amdgcn_cvt_f32_fp8((int)v, 3); }

DI f32x4 MFMA8(long a, long b, f32x4 c){
  return __builtin_amdgcn_mfma_f32_16x16x32_fp8_fp8(a, b, c, 0, 0, 0);
}

// fp8 LDS tile: row stride 256 B; XOR swizzle to the b64 4-way floor
DI int swz8(int row, int col){ return (row << 8) + (col ^ ((row & 15) << 3)); }
DI long ldsA8(const u8* buf, int row, int k0){ return *(const long*)(buf + swz8(row, k0)); }
DI long ldG8(const u8* p){ return *(const long*)p; }

// fallback builders from f32 global (ws too small); scale ×8 like prep
DI long mk8(float v0, float v1, float v2, float v3, float v4, float v5, float v6, float v7){
  u32 lo = pk4f8(v0, v1, v2, v3), hi = pk4f8(v4, v5, v6, v7);
  return (long)(((unsigned long long)hi << 32) | (unsigned long long)lo);
}
DI long loadW8T(const float* __restrict__ W, int n, int k0){
  return mk8(W[(k0+0)*256+n]*8.f, W[(k0+1)*256+n]*8.f, W[(k0+2)*256+n]*8.f, W[(k0+3)*256+n]*8.f,
             W[(k0+4)*256+n]*8.f, W[(k0+5)*256+n]*8.f, W[(k0+6)*256+n]*8.f, W[(k0+7)*256+n]*8.f);
}
DI long loadW8T16(const float* __restrict__ W, int n, int k0){
  float v[8];
#pragma unroll
  for (int j = 0; j < 8; j++){ int k = k0 + j; v[j] = (k < 16) ? W[k*256+n]*8.f : 0.f; }
  return mk8(v[0],v[1],v[2],v[3],v[4],v[5],v[6],v[7]);
}
DI long loadW8row(const float* __restrict__ W, int n, int k0){
  const float* p = W + n*256 + k0;
  return mk8(p[0]*8.f,p[1]*8.f,p[2]*8.f,p[3]*8.f,p[4]*8.f,p[5]*8.f,p[6]*8.f,p[7]*8.f);
}

// d_ws layout (BYTE offsets), all weights fp8 e4m3, pre-scaled x8
#define WS_NEWT  0        // [256][32]  neW^T, K padded 16->32
#define WS_W1AT1 8192     // [256][256] g1W1[0:256]^T
#define WS_W1BT1 73728    // [256][256] g1W1[256:512]^T
#define WS_W2T1  139264   // [256][256] g1W2^T
#define WS_W1AT2 204800
#define WS_W1BT2 270336
#define WS_W2T2  335872
#define WS_PQWT  401408   // [256][256] pqW^T
#define WS_PKWP  466944   // [256][256] pkW plain copy
#define WS_TOTAL 532480

__global__ void prep_weights(
    const float* __restrict__ neW, const float* __restrict__ g1W1,
    const float* __restrict__ g1W2, const float* __restrict__ g2W1,
    const float* __restrict__ g2W2, const float* __restrict__ pqW,
    const float* __restrict__ pkW, u8* __restrict__ ws)
{
  int i = blockIdx.x * 256 + threadIdx.x;
  if (i >= WS_TOTAL) return;
  float v;
  if (i < 8192){
    int n = i >> 5, k = i & 31;
    v = (k < 16) ? neW[k * 256 + n] : 0.0f;
  } else {
    int j = i - 8192;
    int region = j >> 16;
    int idx = j & 65535;
    int n = idx >> 8, k = idx & 255;
    switch (region){
      case 0: v = g1W1[k * 256 + n]; break;
      case 1: v = g1W1[(256 + k) * 256 + n]; break;
      case 2: v = g1W2[k * 256 + n]; break;
      case 3: v = g2W1[k * 256 + n]; break;
      case 4: v = g2W1[(256 + k) * 256 + n]; break;
      case 5: v = g2W2[k * 256 + n]; break;
      case 6: v = pqW[k * 256 + n]; break;
      default: v = pkW[idx]; break;
    }
  }
  ws[i] = enc1(v * 8.0f);
}

// 1 workgroup = 4 batches = 80 rows. 4 waves; wave owns a 64-col N-slice.
// fp8 datapath: bufA = h (20KB), bufB = nf/t1 (20KB). Epilogue scale 0.125.
// Output f32: [oh B*8 | c1 B*10 | c2 B*10 | pl B*20].
template<bool PREPPED>
__global__ __launch_bounds__(256, 3) void fused_graphnet(
    const float* __restrict__ nf, const int* __restrict__ nn_c,
    const float* __restrict__ neW, const float* __restrict__ neb,
    const float* __restrict__ g1W1, const float* __restrict__ g1b1,
    const float* __restrict__ g1W2, const float* __restrict__ g1b2,
    const float* __restrict__ g2W1, const float* __restrict__ g2b1,
    const float* __restrict__ g2W2, const float* __restrict__ g2b2,
    const float* __restrict__ n1g, const float* __restrict__ n1b,
    const float* __restrict__ n2g, const float* __restrict__ n2b,
    const float* __restrict__ ohW, const float* __restrict__ ohb,
    const float* __restrict__ c1W, const float* __restrict__ c1b,
    const float* __restrict__ c2W, const float* __restrict__ c2b,
    const float* __restrict__ pqW, const float* __restrict__ pqb,
    const float* __restrict__ pkW, const float* __restrict__ pkb,
    const u8* __restrict__ ws, float* __restrict__ out,
    int out_n, int Bv)
{
  __shared__ __align__(16) u8 bufA[80 * 256];   // 20KB: h (fp8)
  __shared__ __align__(16) u8 bufB[80 * 256];   // 20KB: nf then t1 (fp8)
  __shared__ __align__(16) u8 smallA[8 * 256];  // 2KB: msg/g rows 0..3, q rows 4..7
  __shared__ float pbf[4 * 256];                // pb then r (f32)
  __shared__ float rowstats[4][80][2];
  __shared__ float qdot[4];
  __shared__ int   cntS[4];
  __shared__ float dinvS[4];

  const int b0 = blockIdx.x * 4;
  const int tid = threadIdx.x;
  const int wave = tid >> 6, lane = tid & 63;
  const int lg = lane >> 4, lc = lane & 15;
  const int n0 = wave * 64;

  const int Bout = out_n / 48;
  const int off_c1 = 8 * Bout;
  const int off_c2 = 18 * Bout;
  const int off_pl = 28 * Bout;

  if (tid < 4){
    int bi = b0 + tid; if (bi >= Bv) bi = Bv - 1;
    int c = nn_c[bi];
    c = c < 0 ? 0 : (c > 20 ? 20 : c);
    cntS[tid] = c;
    dinvS[tid] = 1.0f / (float)(c < 1 ? 1 : c);
  }

  // zero K-pad cols 16..31 of bufB; stage nf (fp8) into cols 0..15
  for (int i = tid; i < 80 * 4; i += 256){
    int row = i >> 2, c0 = 16 + (i & 3) * 4;
    *(u32*)(bufB + swz8(row, c0)) = 0u;
  }
  for (int i = tid; i < 80 * 4; i += 256){
    int row = i >> 2, k0 = (i & 3) * 4;
    int gr = b0 * 20 + row; if (gr >= Bv * 20) gr = Bv * 20 - 1;
    const float* p = nf + gr * 16 + k0;
    *(u32*)(bufB + swz8(row, k0)) = pk4f8(p[0], p[1], p[2], p[3]);
  }
  __syncthreads();   // S1

  const f32x4 zero4 = {0.0f, 0.0f, 0.0f, 0.0f};

  // GEMM0: h0 = nf @ neW + neb (K=32); A from bufB, write h0 -> bufA
  {
    f32x4 acc[5][4];
#pragma unroll
    for (int mt = 0; mt < 5; mt++){
      long a = ldsA8(bufB, mt * 16 + lc, lg * 8);
#pragma unroll
      for (int nt = 0; nt < 4; nt++){
        int n = n0 + nt * 16 + lc;
        long bfr;
        if constexpr (PREPPED) bfr = ldG8(ws + WS_NEWT + n * 32 + lg * 8);
        else bfr = loadW8T16(neW, n, lg * 8);
        acc[mt][nt] = MFMA8(a, bfr, zero4);
      }
    }
#pragma unroll
    for (int nt = 0; nt < 4; nt++){
      float bb = neb[n0 + nt * 16 + lc];
#pragma unroll
      for (int mt = 0; mt < 5; mt++)
#pragma unroll
        for (int r = 0; r < 4; r++){
          int row = mt * 16 + lg * 4 + r;
          int col = n0 + nt * 16 + lc;
          bufA[swz8(row, col)] = enc1(acc[mt][nt][r] * 0.125f + bb);
        }
    }
  }
  __syncthreads();   // S2

  for (int rd = 0; rd < 2; rd++){
    const int w1at = (rd == 0) ? WS_W1AT1 : WS_W1AT2;
    const int w1bt = (rd == 0) ? WS_W1BT1 : WS_W1BT2;
    const int w2t  = (rd == 0) ? WS_W2T1  : WS_W2T2;
    const float* W1 = (rd == 0) ? g1W1 : g2W1;
    const float* W2 = (rd == 0) ? g1W2 : g2W2;
    const float* b1p = (rd == 0) ? g1b1 : g2b1;
    const float* b2p = (rd == 0) ? g1b2 : g2b2;
    const float* ngp = (rd == 0) ? n1g : n2g;
    const float* nbp = (rd == 0) ? n1b : n2b;

    // masked mean of h (bufA) -> smallA rows 0..3
    {
      int b = tid >> 6;
      int c0 = (tid & 63) * 4;
      int c = cntS[b];
      float s0 = 0, s1 = 0, s2 = 0, s3 = 0;
      for (int r = 0; r < c; r++){
        u32 v = *(const u32*)(bufA + swz8(b * 20 + r, c0));
        s0 += dc0(v); s1 += dc1(v); s2 += dc2(v); s3 += dc3(v);
      }
      float di = dinvS[b];
      *(u32*)(smallA + swz8(b, c0)) = pk4f8(s0 * di, s1 * di, s2 * di, s3 * di);
    }
    __syncthreads();   // S3

    // pb = msg @ W1b + b1 -> pbf (lg==0, own cols)
    {
      f32x4 acc[4];
#pragma unroll
      for (int nt = 0; nt < 4; nt++) acc[nt] = zero4;
#pragma unroll
      for (int kk = 0; kk < 8; kk++){
        long a = ldsA8(smallA, lc & 3, kk * 32 + lg * 8);
#pragma unroll
        for (int nt = 0; nt < 4; nt++){
          int n = n0 + nt * 16 + lc;
          long bfr;
          if constexpr (PREPPED) bfr = ldG8(ws + w1bt + n * 256 + kk * 32 + lg * 8);
          else bfr = loadW8T(W1 + 256 * 256, n, kk * 32 + lg * 8);
          acc[nt] = MFMA8(a, bfr, acc[nt]);
        }
      }
      if (lg == 0){
#pragma unroll
        for (int nt = 0; nt < 4; nt++)
#pragma unroll
          for (int r = 0; r < 4; r++){
            int col = n0 + nt * 16 + lc;
            pbf[r * 256 + col] = acc[nt][r] * 0.125f + b1p[col];
          }
      }
    }

    // G1: tacc = h @ W1a ; t1 = relu(tacc*0.125 + pb) -> bufB (no barrier needed)
    {
      f32x4 tacc[5][4];
#pragma unroll
      for (int mt = 0; mt < 5; mt++)
#pragma unroll
        for (int nt = 0; nt < 4; nt++) tacc[mt][nt] = zero4;
#pragma unroll
      for (int kk = 0; kk < 8; kk++){
#pragma unroll
        for (int mt = 0; mt < 5; mt++){
          long a = ldsA8(bufA, mt * 16 + lc, kk * 32 + lg * 8);
#pragma unroll
          for (int nt = 0; nt < 4; nt++){
            int n = n0 + nt * 16 + lc;
            long bfr;
            if constexpr (PREPPED) bfr = ldG8(ws + w1at + n * 256 + kk * 32 + lg * 8);
            else bfr = loadW8T(W1, n, kk * 32 + lg * 8);
            tacc[mt][nt] = MFMA8(a, bfr, tacc[mt][nt]);
          }
        }
      }
#pragma unroll
      for (int mt = 0; mt < 5; mt++)
#pragma unroll
        for (int nt = 0; nt < 4; nt++)
#pragma unroll
          for (int r = 0; r < 4; r++){
            int row = mt * 16 + lg * 4 + r;
            int col = n0 + nt * 16 + lc;
            float v = tacc[mt][nt][r] * 0.125f + pbf[(row / 20) * 256 + col];
            bufB[swz8(row, col)] = enc1(fmaxf(v, 0.0f));
          }
    }
    __syncthreads();   // S4: t1 visible; all G1 h-reads done

    // G2: tacc = t1 @ W2 ; v = tacc*0.125 + residual(bufA) + b2 ; LN ; h_new -> bufA
    {
      f32x4 tacc[5][4];
#pragma unroll
      for (int mt = 0; mt < 5; mt++)
#pragma unroll
        for (int nt = 0; nt < 4; nt++) tacc[mt][nt] = zero4;
#pragma unroll
      for (int kk = 0; kk < 8; kk++){
#pragma unroll
        for (int mt = 0; mt < 5; mt++){
          long a = ldsA8(bufB, mt * 16 + lc, kk * 32 + lg * 8);
#pragma unroll
          for (int nt = 0; nt < 4; nt++){
            int n = n0 + nt * 16 + lc;
            long bfr;
            if constexpr (PREPPED) bfr = ldG8(ws + w2t + n * 256 + kk * 32 + lg * 8);
            else bfr = loadW8T(W2, n, kk * 32 + lg * 8);
            tacc[mt][nt] = MFMA8(a, bfr, tacc[mt][nt]);
          }
        }
      }
      // + residual + b2 (own cols of bufA, byte reads)
#pragma unroll
      for (int nt = 0; nt < 4; nt++){
        float b2s = b2p[n0 + nt * 16 + lc];
#pragma unroll
        for (int mt = 0; mt < 5; mt++)
#pragma unroll
          for (int r = 0; r < 4; r++){
            int row = mt * 16 + lg * 4 + r;
            int col = n0 + nt * 16 + lc;
            u32 rv = bufA[swz8(row, col)];
            tacc[mt][nt][r] = tacc[mt][nt][r] * 0.125f + dc0(rv) + b2s;
          }
      }

      // LN stats (f32, from regs)
#pragma unroll
      for (int mt = 0; mt < 5; mt++)
#pragma unroll
        for (int r = 0; r < 4; r++){
          int row = mt * 16 + lg * 4 + r;
          float s1 = 0, s2 = 0;
#pragma unroll
          for (int nt = 0; nt < 4; nt++){ float v = tacc[mt][nt][r]; s1 += v; s2 += v * v; }
#pragma unroll
          for (int d = 1; d < 16; d <<= 1){ s1 += __shfl_xor(s1, d, 64); s2 += __shfl_xor(s2, d, 64); }
          if (lc == 0){ rowstats[wave][row][0] = s1; rowstats[wave][row][1] = s2; }
        }
      __syncthreads();   // S5

      float ngv[4], nbv[4];
#pragma unroll
      for (int nt = 0; nt < 4; nt++){
        ngv[nt] = ngp[n0 + nt * 16 + lc];
        nbv[nt] = nbp[n0 + nt * 16 + lc];
      }
#pragma unroll
      for (int mt = 0; mt < 5; mt++)
#pragma unroll
        for (int r = 0; r < 4; r++){
          int row = mt * 16 + lg * 4 + r;
          float t1s = rowstats[0][row][0] + rowstats[1][row][0] + rowstats[2][row][0] + rowstats[3][row][0];
          float t2s = rowstats[0][row][1] + rowstats[1][row][1] + rowstats[2][row][1] + rowstats[3][row][1];
          float mean = t1s * (1.0f / 256.0f);
          float var  = t2s * (1.0f / 256.0f) - mean * mean;
          float rstd = rsqrtf(fmaxf(var, 0.0f) + 1e-5f);
          int bb = row / 20;
          float mf = ((row - bb * 20) < cntS[bb]) ? 1.0f : 0.0f;
#pragma unroll
          for (int nt = 0; nt < 4; nt++){
            int col = n0 + nt * 16 + lc;
            float v = ((tacc[mt][nt][r] - mean) * rstd * ngv[nt] + nbv[nt]) * mf;
            bufA[swz8(row, col)] = enc1(v);
          }
        }
    }
    __syncthreads();   // S6
  }

  // g = masked mean -> smallA rows 0..3
  {
    int b = tid >> 6;
    int c0 = (tid & 63) * 4;
    int c = cntS[b];
    float s0 = 0, s1 = 0, s2 = 0, s3 = 0;
    for (int r = 0; r < c; r++){
      u32 v = *(const u32*)(bufA + swz8(b * 20 + r, c0));
      s0 += dc0(v); s1 += dc1(v); s2 += dc2(v); s3 += dc3(v);
    }
    float di = dinvS[b];
    *(u32*)(smallA + swz8(b, c0)) = pk4f8(s0 * di, s1 * di, s2 * di, s3 * di);
  }
  __syncthreads();   // S7

  // q = g @ pqW + pqb -> smallA rows 4..7
  {
    f32x4 qacc[4];
#pragma unroll
    for (int nt = 0; nt < 4; nt++) qacc[nt] = zero4;
#pragma unroll
    for (int kk = 0; kk < 8; kk++){
      long a = ldsA8(smallA, lc & 3, kk * 32 + lg * 8);
#pragma unroll
      for (int nt = 0; nt < 4; nt++){
        int n = n0 + nt * 16 + lc;
        long bfr;
        if constexpr (PREPPED) bfr = ldG8(ws + WS_PQWT + n * 256 + kk * 32 + lg * 8);
        else bfr = loadW8T(pqW, n, kk * 32 + lg * 8);
        qacc[nt] = MFMA8(a, bfr, qacc[nt]);
      }
    }
    if (lg == 0){
#pragma unroll
      for (int nt = 0; nt < 4; nt++)
#pragma unroll
        for (int r = 0; r < 4; r++){
          int col = n0 + nt * 16 + lc;
          smallA[swz8(4 + r, col)] = enc1(qacc[nt][r] * 0.125f + pqb[col]);
        }
    }
  }
  __syncthreads();   // S8

  // qdot[b] = q[b].pkb (wave w = batch w)
  {
    u32 qv = *(const u32*)(smallA + swz8(4 + wave, lane * 4));
    float p = dc0(qv) * pkb[lane * 4 + 0] + dc1(qv) * pkb[lane * 4 + 1]
            + dc2(qv) * pkb[lane * 4 + 2] + dc3(qv) * pkb[lane * 4 + 3];
#pragma unroll
    for (int d = 1; d < 64; d <<= 1) p += __shfl_xor(p, d, 64);
    if (lane == 0) qdot[wave] = p;
  }

  // r[b][n] = sum_k q[b][k]*pkW[n][k] -> pbf
  {
    f32x4 racc[4];
#pragma unroll
    for (int nt = 0; nt < 4; nt++) racc[nt] = zero4;
#pragma unroll
    for (int kk = 0; kk < 8; kk++){
      long a = ldsA8(smallA, 4 + (lc & 3), kk * 32 + lg * 8);
#pragma unroll
      for (int nt = 0; nt < 4; nt++){
        int n = n0 + nt * 16 + lc;
        long bfr;
        if constexpr (PREPPED) bfr = ldG8(ws + WS_PKWP + n * 256 + kk * 32 + lg * 8);
        else bfr = loadW8row(pkW, n, kk * 32 + lg * 8);
        racc[nt] = MFMA8(a, bfr, racc[nt]);
      }
    }
    if (lg == 0){
#pragma unroll
      for (int nt = 0; nt < 4; nt++)
#pragma unroll
        for (int r = 0; r < 4; r++)
          pbf[r * 256 + (n0 + nt * 16 + lc)] = racc[nt][r] * 0.125f;
    }
  }
  __syncthreads();   // S9

  // pl[b,n] = h[row].r[b] + qdot[b] (masked -> exactly -1e9)
  {
    const int b = wave;
    if (b0 + b < Bv){
      int cb = cntS[b];
      float qd = qdot[b];
      for (int rr = 0; rr < 20; rr++){
        int row = b * 20 + rr;
        u32 hv = *(const u32*)(bufA + swz8(row, lane * 4));
        const float* rp = pbf + b * 256 + lane * 4;
        float p = dc0(hv) * rp[0] + dc1(hv) * rp[1] + dc2(hv) * rp[2] + dc3(hv) * rp[3];
#pragma unroll
        for (int d = 1; d < 64; d <<= 1) p += __shfl_xor(p, d, 64);
        if (lane == 0){
          float v = (rr < cb) ? (p + qd) : -1e9f;
          out[off_pl + (b0 + b) * 20 + rr] = v;
        }
      }
    }
  }

  // heads (wave w = batch w): oh [B,8]@0, c1 [B,10]@off_c1, c2 [B,10]@off_c2
  {
    const int b = wave;
    if (b0 + b < Bv){
      u32 gv = *(const u32*)(smallA + swz8(b, lane * 4));
      float g0 = dc0(gv), g1 = dc1(gv), g2 = dc2(gv), g3 = dc3(gv);
#pragma unroll
      for (int o = 0; o < 28; o++){
        const float* W; const float* bias; int ncol, col, off;
        if (o < 8)      { W = ohW; bias = ohb; ncol = 8;  col = o;      off = 0; }
        else if (o < 18){ W = c1W; bias = c1b; ncol = 10; col = o - 8;  off = off_c1; }
        else            { W = c2W; bias = c2b; ncol = 10; col = o - 18; off = off_c2; }
        int k = lane * 4;
        float p = g0 * W[(k + 0) * ncol + col] + g1 * W[(k + 1) * ncol + col]
                + g2 * W[(k + 2) * ncol + col] + g3 * W[(k + 3) * ncol + col];
#pragma unroll
        for (int d = 1; d < 64; d <<= 1) p += __shfl_xor(p, d, 64);
        if (lane == 0) out[off + (b0 + b) * ncol + col] = p + bias[col];
      }
    }
  }
}

extern "C" void kernel_launch(void* const* d_in, const int* in_sizes, int n_in,
                              void* d_out, int out_size, void* d_ws, size_t ws_size,
                              hipStream_t stream)
{
  const float* nf   = (const float*)d_in[0];
  const int*   nn_c = (const int*)d_in[1];
  const float* neW  = (const float*)d_in[2];
  const float* neb  = (const float*)d_in[3];
  const float* g1W1 = (const float*)d_in[4];
  const float* g1b1 = (const float*)d_in[5];
  const float* g1W2 = (const float*)d_in[6];
  const float* g1b2 = (const float*)d_in[7];
  const float* g2W1 = (const float*)d_in[8];
  const float* g2b1 = (const float*)d_in[9];
  const float* g2W2 = (const float*)d_in[10];
  const float* g2b2 = (const float*)d_in[11];
  const float* n1g  = (const float*)d_in[12];
  const float* n1b  = (const float*)d_in[13];
  const float* n2g  = (const float*)d_in[14];
  const float* n2b  = (const float*)d_in[15];
  const float* ohW  = (const float*)d_in[16];
  const float* ohb  = (const float*)d_in[17];
  const float* c1W  = (const float*)d_in[18];
  const float* c1b  = (const float*)d_in[19];
  const float* c2W  = (const float*)d_in[20];
  const float* c2b  = (const float*)d_in[21];
  const float* pqW  = (const float*)d_in[22];
  const float* pqb  = (const float*)d_in[23];
  const float* pkW  = (const float*)d_in[24];
  const float* pkb  = (const float*)d_in[25];

  float* outp = (float*)d_out;
  u8* ws = (u8*)d_ws;
  int B = in_sizes[0] / 320;       // nf is [B,20,16]
  int grid = (B + 3) / 4;

  if (ws_size >= (size_t)WS_TOTAL){
    prep_weights<<<(WS_TOTAL + 255) / 256, 256, 0, stream>>>(
        neW, g1W1, g1W2, g2W1, g2W2, pqW, pkW, ws);
    fused_graphnet<true><<<grid, 256, 0, stream>>>(
        nf, nn_c, neW, neb, g1W1, g1b1, g1W2, g1b2, g2W1, g2b1, g2W2, g2b2,
        n1g, n1b, n2g, n2b, ohW, ohb, c1W, c1b, c2W, c2b, pqW, pqb, pkW, pkb,
        ws, outp, out_size, B);
  } else {
    fused_graphnet<false><<<grid, 256, 0, stream>>>(
        nf, nn_c, neW, neb, g1W1, g1b1, g1W2, g1b2, g2W1, g2b1, g2W2, g2b2,
        n1g, n1b, n2g, n2b, ohW, ohb, c1W, c1b, c2W, c2b, pqW, pqb, pkW, pkb,
        ws, outp, out_size, B);
  }
}

// Round 10
// 1167.713 us; speedup vs baseline: 2.0346x; 1.4888x over previous
//
#include <hip/hip_runtime.h>

typedef unsigned char u8;
typedef unsigned int  u32;
using f32x4 = __attribute__((ext_vector_type(4))) float;

#define DI __device__ __forceinline__

// ---- fp8 e4m3 (OCP on gfx950) HW converts ----
DI u32 pk4f8(float a, float b, float c, float d){
  int w = __builtin_amdgcn_cvt_pk_fp8_f32(a, b, 0, false);
  w = __builtin_amdgcn_cvt_pk_fp8_f32(c, d, w, true);
  return (u32)w;
}
DI u8 enc1(float a){
  return (u8)(__builtin_amdgcn_cvt_pk_fp8_f32(a, a, 0, false) & 0xFF);
}
DI float dc0(u32 v){ return __builtin_amdgcn_cvt_f32_fp8((int)v, 0); }
DI float dc1(u32 v){ return __builtin_amdgcn_cvt_f32_fp8((int)v, 1); }
DI float dc2(u32 v){ return __builtin_amdgcn_cvt_f32_fp8((int)v, 2); }
DI float dc3(u32 v){ return __builtin_amdgcn_cvt_f32_fp8((int)v, 3); }

DI f32x4 MFMA8(long a, long b, f32x4 c){
  return __builtin_amdgcn_mfma_f32_16x16x32_fp8_fp8(a, b, c, 0, 0, 0);
}

// fp8 LDS tile: row stride 256 B; XOR swizzle
DI int swz8(int row, int col){ return (row << 8) + (col ^ ((row & 15) << 3)); }
DI long ldsA8(const u8* buf, int row, int k0){ return *(const long*)(buf + swz8(row, k0)); }
DI long ldG8(const u8* p){ return *(const long*)p; }

// fallback builders from f32 global (ws too small); scale ×8 like prep
DI long mk8(float v0, float v1, float v2, float v3, float v4, float v5, float v6, float v7){
  u32 lo = pk4f8(v0, v1, v2, v3), hi = pk4f8(v4, v5, v6, v7);
  return (long)(((unsigned long long)hi << 32) | (unsigned long long)lo);
}
DI long loadW8T(const float* __restrict__ W, int n, int k0){
  return mk8(W[(k0+0)*256+n]*8.f, W[(k0+1)*256+n]*8.f, W[(k0+2)*256+n]*8.f, W[(k0+3)*256+n]*8.f,
             W[(k0+4)*256+n]*8.f, W[(k0+5)*256+n]*8.f, W[(k0+6)*256+n]*8.f, W[(k0+7)*256+n]*8.f);
}
DI long loadW8T16(const float* __restrict__ W, int n, int k0){
  float v[8];
#pragma unroll
  for (int j = 0; j < 8; j++){ int k = k0 + j; v[j] = (k < 16) ? W[k*256+n]*8.f : 0.f; }
  return mk8(v[0],v[1],v[2],v[3],v[4],v[5],v[6],v[7]);
}
DI long loadW8row(const float* __restrict__ W, int n, int k0){
  const float* p = W + n*256 + k0;
  return mk8(p[0]*8.f,p[1]*8.f,p[2]*8.f,p[3]*8.f,p[4]*8.f,p[5]*8.f,p[6]*8.f,p[7]*8.f);
}

// d_ws layout (BYTE offsets), all weights fp8 e4m3, pre-scaled x8
#define WS_NEWT  0        // [256][32]  neW^T, K padded 16->32
#define WS_W1AT1 8192     // [256][256] g1W1[0:256]^T
#define WS_W1BT1 73728    // [256][256] g1W1[256:512]^T
#define WS_W2T1  139264   // [256][256] g1W2^T
#define WS_W1AT2 204800
#define WS_W1BT2 270336
#define WS_W2T2  335872
#define WS_PQWT  401408   // [256][256] pqW^T
#define WS_PKWP  466944   // [256][256] pkW plain copy
#define WS_TOTAL 532480

__global__ void prep_weights(
    const float* __restrict__ neW, const float* __restrict__ g1W1,
    const float* __restrict__ g1W2, const float* __restrict__ g2W1,
    const float* __restrict__ g2W2, const float* __restrict__ pqW,
    const float* __restrict__ pkW, u8* __restrict__ ws)
{
  int i = blockIdx.x * 256 + threadIdx.x;
  if (i >= WS_TOTAL) return;
  float v;
  if (i < 8192){
    int n = i >> 5, k = i & 31;
    v = (k < 16) ? neW[k * 256 + n] : 0.0f;
  } else {
    int j = i - 8192;
    int region = j >> 16;
    int idx = j & 65535;
    int n = idx >> 8, k = idx & 255;
    switch (region){
      case 0: v = g1W1[k * 256 + n]; break;
      case 1: v = g1W1[(256 + k) * 256 + n]; break;
      case 2: v = g1W2[k * 256 + n]; break;
      case 3: v = g2W1[k * 256 + n]; break;
      case 4: v = g2W1[(256 + k) * 256 + n]; break;
      case 5: v = g2W2[k * 256 + n]; break;
      case 6: v = pqW[k * 256 + n]; break;
      default: v = pkW[idx]; break;
    }
  }
  ws[i] = enc1(v * 8.0f);
}

// 1 workgroup = 4 batches = 80 rows. 4 waves; wave owns a 64-col N-slice,
// processed as two sequential 32-col halves (tacc[5][2] = 40 VGPR live max).
// Output f32: [oh B*8 | c1 B*10 | c2 B*10 | pl B*20].
template<bool PREPPED>
__global__ __launch_bounds__(256, 3) void fused_graphnet(
    const float* __restrict__ nf, const int* __restrict__ nn_c,
    const float* __restrict__ neW, const float* __restrict__ neb,
    const float* __restrict__ g1W1, const float* __restrict__ g1b1,
    const float* __restrict__ g1W2, const float* __restrict__ g1b2,
    const float* __restrict__ g2W1, const float* __restrict__ g2b1,
    const float* __restrict__ g2W2, const float* __restrict__ g2b2,
    const float* __restrict__ n1g, const float* __restrict__ n1b,
    const float* __restrict__ n2g, const float* __restrict__ n2b,
    const float* __restrict__ ohW, const float* __restrict__ ohb,
    const float* __restrict__ c1W, const float* __restrict__ c1b,
    const float* __restrict__ c2W, const float* __restrict__ c2b,
    const float* __restrict__ pqW, const float* __restrict__ pqb,
    const float* __restrict__ pkW, const float* __restrict__ pkb,
    const u8* __restrict__ ws, float* __restrict__ out,
    int out_n, int Bv)
{
  __shared__ __align__(16) u8 bufA[80 * 256];   // 20KB: h / pre-LN v (fp8)
  __shared__ __align__(16) u8 bufB[80 * 256];   // 20KB: nf then t1 (fp8)
  __shared__ __align__(16) u8 smallA[8 * 256];  // 2KB: msg/g rows 0..3, q rows 4..7
  __shared__ float pbf[4 * 256];                // pb then r (f32)
  __shared__ float rowstats[4][80][2];
  __shared__ float qdot[4];
  __shared__ int   cntS[4];
  __shared__ float dinvS[4];

  const int b0 = blockIdx.x * 4;
  const int tid = threadIdx.x;
  const int wave = tid >> 6, lane = tid & 63;
  const int lg = lane >> 4, lc = lane & 15;
  const int n0 = wave * 64;

  const int Bout = out_n / 48;
  const int off_c1 = 8 * Bout;
  const int off_c2 = 18 * Bout;
  const int off_pl = 28 * Bout;

  if (tid < 4){
    int bi = b0 + tid; if (bi >= Bv) bi = Bv - 1;
    int c = nn_c[bi];
    c = c < 0 ? 0 : (c > 20 ? 20 : c);
    cntS[tid] = c;
    dinvS[tid] = 1.0f / (float)(c < 1 ? 1 : c);
  }

  // zero K-pad cols 16..31 of bufB; stage nf (fp8) into cols 0..15
  for (int i = tid; i < 80 * 4; i += 256){
    int row = i >> 2, c0 = 16 + (i & 3) * 4;
    *(u32*)(bufB + swz8(row, c0)) = 0u;
  }
  for (int i = tid; i < 80 * 4; i += 256){
    int row = i >> 2, k0 = (i & 3) * 4;
    int gr = b0 * 20 + row; if (gr >= Bv * 20) gr = Bv * 20 - 1;
    const float* p = nf + gr * 16 + k0;
    *(u32*)(bufB + swz8(row, k0)) = pk4f8(p[0], p[1], p[2], p[3]);
  }
  __syncthreads();   // S1

  const f32x4 zero4 = {0.0f, 0.0f, 0.0f, 0.0f};

  // GEMM0: h0 = nf @ neW + neb (K=32); two N-halves; A from bufB, h0 -> bufA
#pragma unroll
  for (int nh = 0; nh < 2; nh++){
    const int n0h = n0 + nh * 32;
    f32x4 acc[5][2];
#pragma unroll
    for (int mt = 0; mt < 5; mt++){
      long a = ldsA8(bufB, mt * 16 + lc, lg * 8);
#pragma unroll
      for (int nt = 0; nt < 2; nt++){
        int n = n0h + nt * 16 + lc;
        long bfr;
        if constexpr (PREPPED) bfr = ldG8(ws + WS_NEWT + n * 32 + lg * 8);
        else bfr = loadW8T16(neW, n, lg * 8);
        acc[mt][nt] = MFMA8(a, bfr, zero4);
      }
    }
#pragma unroll
    for (int nt = 0; nt < 2; nt++){
      float bb = neb[n0h + nt * 16 + lc];
#pragma unroll
      for (int mt = 0; mt < 5; mt++)
#pragma unroll
        for (int r = 0; r < 4; r++){
          int row = mt * 16 + lg * 4 + r;
          int col = n0h + nt * 16 + lc;
          bufA[swz8(row, col)] = enc1(acc[mt][nt][r] * 0.125f + bb);
        }
    }
  }
  __syncthreads();   // S2

  for (int rd = 0; rd < 2; rd++){
    const int w1at = (rd == 0) ? WS_W1AT1 : WS_W1AT2;
    const int w1bt = (rd == 0) ? WS_W1BT1 : WS_W1BT2;
    const int w2t  = (rd == 0) ? WS_W2T1  : WS_W2T2;
    const float* W1 = (rd == 0) ? g1W1 : g2W1;
    const float* W2 = (rd == 0) ? g1W2 : g2W2;
    const float* b1p = (rd == 0) ? g1b1 : g2b1;
    const float* b2p = (rd == 0) ? g1b2 : g2b2;
    const float* ngp = (rd == 0) ? n1g : n2g;
    const float* nbp = (rd == 0) ? n1b : n2b;

    // masked mean of h (bufA) -> smallA rows 0..3
    {
      int b = tid >> 6;
      int c0 = (tid & 63) * 4;
      int c = cntS[b];
      float s0 = 0, s1 = 0, s2 = 0, s3 = 0;
      for (int r = 0; r < c; r++){
        u32 v = *(const u32*)(bufA + swz8(b * 20 + r, c0));
        s0 += dc0(v); s1 += dc1(v); s2 += dc2(v); s3 += dc3(v);
      }
      float di = dinvS[b];
      *(u32*)(smallA + swz8(b, c0)) = pk4f8(s0 * di, s1 * di, s2 * di, s3 * di);
    }
    __syncthreads();   // S3

    // pb = msg @ W1b + b1 -> pbf (lg==0, own cols); two N-halves
#pragma unroll
    for (int nh = 0; nh < 2; nh++){
      const int n0h = n0 + nh * 32;
      f32x4 acc[2];
#pragma unroll
      for (int nt = 0; nt < 2; nt++) acc[nt] = zero4;
#pragma unroll
      for (int kk = 0; kk < 8; kk++){
        long a = ldsA8(smallA, lc & 3, kk * 32 + lg * 8);
#pragma unroll
        for (int nt = 0; nt < 2; nt++){
          int n = n0h + nt * 16 + lc;
          long bfr;
          if constexpr (PREPPED) bfr = ldG8(ws + w1bt + n * 256 + kk * 32 + lg * 8);
          else bfr = loadW8T(W1 + 256 * 256, n, kk * 32 + lg * 8);
          acc[nt] = MFMA8(a, bfr, acc[nt]);
        }
      }
      if (lg == 0){
#pragma unroll
        for (int nt = 0; nt < 2; nt++)
#pragma unroll
          for (int r = 0; r < 4; r++){
            int col = n0h + nt * 16 + lc;
            pbf[r * 256 + col] = acc[nt][r] * 0.125f + b1p[col];
          }
      }
    }

    // G1: t1 = relu(h @ W1a * 0.125 + pb) -> bufB; two N-halves
#pragma unroll
    for (int nh = 0; nh < 2; nh++){
      const int n0h = n0 + nh * 32;
      f32x4 tacc[5][2];
#pragma unroll
      for (int mt = 0; mt < 5; mt++)
#pragma unroll
        for (int nt = 0; nt < 2; nt++) tacc[mt][nt] = zero4;
#pragma unroll
      for (int kk = 0; kk < 8; kk++){
#pragma unroll
        for (int mt = 0; mt < 5; mt++){
          long a = ldsA8(bufA, mt * 16 + lc, kk * 32 + lg * 8);
#pragma unroll
          for (int nt = 0; nt < 2; nt++){
            int n = n0h + nt * 16 + lc;
            long bfr;
            if constexpr (PREPPED) bfr = ldG8(ws + w1at + n * 256 + kk * 32 + lg * 8);
            else bfr = loadW8T(W1, n, kk * 32 + lg * 8);
            tacc[mt][nt] = MFMA8(a, bfr, tacc[mt][nt]);
          }
        }
      }
#pragma unroll
      for (int mt = 0; mt < 5; mt++)
#pragma unroll
        for (int nt = 0; nt < 2; nt++)
#pragma unroll
          for (int r = 0; r < 4; r++){
            int row = mt * 16 + lg * 4 + r;
            int col = n0h + nt * 16 + lc;
            float v = tacc[mt][nt][r] * 0.125f + pbf[(row / 20) * 256 + col];
            bufB[swz8(row, col)] = enc1(fmaxf(v, 0.0f));
          }
    }
    __syncthreads();   // S4: t1 visible; all G1 h-reads done

    // G2: v = t1 @ W2 * 0.125 + residual(bufA) + b2 -> bufA (own cols, pre-LN)
#pragma unroll
    for (int nh = 0; nh < 2; nh++){
      const int n0h = n0 + nh * 32;
      f32x4 tacc[5][2];
#pragma unroll
      for (int mt = 0; mt < 5; mt++)
#pragma unroll
        for (int nt = 0; nt < 2; nt++) tacc[mt][nt] = zero4;
#pragma unroll
      for (int kk = 0; kk < 8; kk++){
#pragma unroll
        for (int mt = 0; mt < 5; mt++){
          long a = ldsA8(bufB, mt * 16 + lc, kk * 32 + lg * 8);
#pragma unroll
          for (int nt = 0; nt < 2; nt++){
            int n = n0h + nt * 16 + lc;
            long bfr;
            if constexpr (PREPPED) bfr = ldG8(ws + w2t + n * 256 + kk * 32 + lg * 8);
            else bfr = loadW8T(W2, n, kk * 32 + lg * 8);
            tacc[mt][nt] = MFMA8(a, bfr, tacc[mt][nt]);
          }
        }
      }
#pragma unroll
      for (int nt = 0; nt < 2; nt++){
        float b2s = b2p[n0h + nt * 16 + lc];
#pragma unroll
        for (int mt = 0; mt < 5; mt++)
#pragma unroll
          for (int r = 0; r < 4; r++){
            int row = mt * 16 + lg * 4 + r;
            int col = n0h + nt * 16 + lc;
            u32 rv = bufA[swz8(row, col)];              // residual (same thread wrote it)
            float v = tacc[mt][nt][r] * 0.125f + dc0(rv) + b2s;
            bufA[swz8(row, col)] = enc1(v);             // pre-LN v, own cols
          }
      }
    }

    // LN: stats from bufA (own cols, same-thread RAW -> no barrier needed yet)
    {
#pragma unroll
      for (int mt = 0; mt < 5; mt++)
#pragma unroll
        for (int r = 0; r < 4; r++){
          int row = mt * 16 + lg * 4 + r;
          float s1 = 0, s2 = 0;
#pragma unroll
          for (int nt = 0; nt < 4; nt++){
            float v = dc0((u32)bufA[swz8(row, n0 + nt * 16 + lc)]);
            s1 += v; s2 += v * v;
          }
#pragma unroll
          for (int d = 1; d < 16; d <<= 1){ s1 += __shfl_xor(s1, d, 64); s2 += __shfl_xor(s2, d, 64); }
          if (lc == 0){ rowstats[wave][row][0] = s1; rowstats[wave][row][1] = s2; }
        }
      __syncthreads();   // S5

      float ngv[4], nbv[4];
#pragma unroll
      for (int nt = 0; nt < 4; nt++){
        ngv[nt] = ngp[n0 + nt * 16 + lc];
        nbv[nt] = nbp[n0 + nt * 16 + lc];
      }
#pragma unroll
      for (int mt = 0; mt < 5; mt++)
#pragma unroll
        for (int r = 0; r < 4; r++){
          int row = mt * 16 + lg * 4 + r;
          float t1s = rowstats[0][row][0] + rowstats[1][row][0] + rowstats[2][row][0] + rowstats[3][row][0];
          float t2s = rowstats[0][row][1] + rowstats[1][row][1] + rowstats[2][row][1] + rowstats[3][row][1];
          float mean = t1s * (1.0f / 256.0f);
          float var  = t2s * (1.0f / 256.0f) - mean * mean;
          float rstd = rsqrtf(fmaxf(var, 0.0f) + 1e-5f);
          int bb = row / 20;
          float mf = ((row - bb * 20) < cntS[bb]) ? 1.0f : 0.0f;
#pragma unroll
          for (int nt = 0; nt < 4; nt++){
            int col = n0 + nt * 16 + lc;
            float v = dc0((u32)bufA[swz8(row, col)]);
            bufA[swz8(row, col)] = enc1(((v - mean) * rstd * ngv[nt] + nbv[nt]) * mf);
          }
        }
    }
    __syncthreads();   // S6
  }

  // g = masked mean -> smallA rows 0..3
  {
    int b = tid >> 6;
    int c0 = (tid & 63) * 4;
    int c = cntS[b];
    float s0 = 0, s1 = 0, s2 = 0, s3 = 0;
    for (int r = 0; r < c; r++){
      u32 v = *(const u32*)(bufA + swz8(b * 20 + r, c0));
      s0 += dc0(v); s1 += dc1(v); s2 += dc2(v); s3 += dc3(v);
    }
    float di = dinvS[b];
    *(u32*)(smallA + swz8(b, c0)) = pk4f8(s0 * di, s1 * di, s2 * di, s3 * di);
  }
  __syncthreads();   // S7

  // q = g @ pqW + pqb -> smallA rows 4..7
  {
    f32x4 qacc[4];
#pragma unroll
    for (int nt = 0; nt < 4; nt++) qacc[nt] = zero4;
#pragma unroll
    for (int kk = 0; kk < 8; kk++){
      long a = ldsA8(smallA, lc & 3, kk * 32 + lg * 8);
#pragma unroll
      for (int nt = 0; nt < 4; nt++){
        int n = n0 + nt * 16 + lc;
        long bfr;
        if constexpr (PREPPED) bfr = ldG8(ws + WS_PQWT + n * 256 + kk * 32 + lg * 8);
        else bfr = loadW8T(pqW, n, kk * 32 + lg * 8);
        qacc[nt] = MFMA8(a, bfr, qacc[nt]);
      }
    }
    if (lg == 0){
#pragma unroll
      for (int nt = 0; nt < 4; nt++)
#pragma unroll
        for (int r = 0; r < 4; r++){
          int col = n0 + nt * 16 + lc;
          smallA[swz8(4 + r, col)] = enc1(qacc[nt][r] * 0.125f + pqb[col]);
        }
    }
  }
  __syncthreads();   // S8

  // qdot[b] = q[b].pkb (wave w = batch w)
  {
    u32 qv = *(const u32*)(smallA + swz8(4 + wave, lane * 4));
    float p = dc0(qv) * pkb[lane * 4 + 0] + dc1(qv) * pkb[lane * 4 + 1]
            + dc2(qv) * pkb[lane * 4 + 2] + dc3(qv) * pkb[lane * 4 + 3];
#pragma unroll
    for (int d = 1; d < 64; d <<= 1) p += __shfl_xor(p, d, 64);
    if (lane == 0) qdot[wave] = p;
  }

  // r[b][n] = sum_k q[b][k]*pkW[n][k] -> pbf
  {
    f32x4 racc[4];
#pragma unroll
    for (int nt = 0; nt < 4; nt++) racc[nt] = zero4;
#pragma unroll
    for (int kk = 0; kk < 8; kk++){
      long a = ldsA8(smallA, 4 + (lc & 3), kk * 32 + lg * 8);
#pragma unroll
      for (int nt = 0; nt < 4; nt++){
        int n = n0 + nt * 16 + lc;
        long bfr;
        if constexpr (PREPPED) bfr = ldG8(ws + WS_PKWP + n * 256 + kk * 32 + lg * 8);
        else bfr = loadW8row(pkW, n, kk * 32 + lg * 8);
        racc[nt] = MFMA8(a, bfr, racc[nt]);
      }
    }
    if (lg == 0){
#pragma unroll
      for (int nt = 0; nt < 4; nt++)
#pragma unroll
        for (int r = 0; r < 4; r++)
          pbf[r * 256 + (n0 + nt * 16 + lc)] = racc[nt][r] * 0.125f;
    }
  }
  __syncthreads();   // S9

  // pl[b,n] = h[row].r[b] + qdot[b] (masked -> exactly -1e9)
  {
    const int b = wave;
    if (b0 + b < Bv){
      int cb = cntS[b];
      float qd = qdot[b];
      for (int rr = 0; rr < 20; rr++){
        int row = b * 20 + rr;
        u32 hv = *(const u32*)(bufA + swz8(row, lane * 4));
        const float* rp = pbf + b * 256 + lane * 4;
        float p = dc0(hv) * rp[0] + dc1(hv) * rp[1] + dc2(hv) * rp[2] + dc3(hv) * rp[3];
#pragma unroll
        for (int d = 1; d < 64; d <<= 1) p += __shfl_xor(p, d, 64);
        if (lane == 0){
          float v = (rr < cb) ? (p + qd) : -1e9f;
          out[off_pl + (b0 + b) * 20 + rr] = v;
        }
      }
    }
  }

  // heads (wave w = batch w): oh [B,8]@0, c1 [B,10]@off_c1, c2 [B,10]@off_c2
  {
    const int b = wave;
    if (b0 + b < Bv){
      u32 gv = *(const u32*)(smallA + swz8(b, lane * 4));
      float g0 = dc0(gv), g1 = dc1(gv), g2 = dc2(gv), g3 = dc3(gv);
#pragma unroll
      for (int o = 0; o < 28; o++){
        const float* W; const float* bias; int ncol, col, off;
        if (o < 8)      { W = ohW; bias = ohb; ncol = 8;  col = o;      off = 0; }
        else if (o < 18){ W = c1W; bias = c1b; ncol = 10; col = o - 8;  off = off_c1; }
        else            { W = c2W; bias = c2b; ncol = 10; col = o - 18; off = off_c2; }
        int k = lane * 4;
        float p = g0 * W[(k + 0) * ncol + col] + g1 * W[(k + 1) * ncol + col]
                + g2 * W[(k + 2) * ncol + col] + g3 * W[(k + 3) * ncol + col];
#pragma unroll
        for (int d = 1; d < 64; d <<= 1) p += __shfl_xor(p, d, 64);
        if (lane == 0) out[off + (b0 + b) * ncol + col] = p + bias[col];
      }
    }
  }
}

extern "C" void kernel_launch(void* const* d_in, const int* in_sizes, int n_in,
                              void* d_out, int out_size, void* d_ws, size_t ws_size,
                              hipStream_t stream)
{
  const float* nf   = (const float*)d_in[0];
  const int*   nn_c = (const int*)d_in[1];
  const float* neW  = (const float*)d_in[2];
  const float* neb  = (const float*)d_in[3];
  const float* g1W1 = (const float*)d_in[4];
  const float* g1b1 = (const float*)d_in[5];
  const float* g1W2 = (const float*)d_in[6];
  const float* g1b2 = (const float*)d_in[7];
  const float* g2W1 = (const float*)d_in[8];
  const float* g2b1 = (const float*)d_in[9];
  const float* g2W2 = (const float*)d_in[10];
  const float* g2b2 = (const float*)d_in[11];
  const float* n1g  = (const float*)d_in[12];
  const float* n1b  = (const float*)d_in[13];
  const float* n2g  = (const float*)d_in[14];
  const float* n2b  = (const float*)d_in[15];
  const float* ohW  = (const float*)d_in[16];
  const float* ohb  = (const float*)d_in[17];
  const float* c1W  = (const float*)d_in[18];
  const float* c1b  = (const float*)d_in[19];
  const float* c2W  = (const float*)d_in[20];
  const float* c2b  = (const float*)d_in[21];
  const float* pqW  = (const float*)d_in[22];
  const float* pqb  = (const float*)d_in[23];
  const float* pkW  = (const float*)d_in[24];
  const float* pkb  = (const float*)d_in[25];

  float* outp = (float*)d_out;
  u8* ws = (u8*)d_ws;
  int B = in_sizes[0] / 320;       // nf is [B,20,16]
  int grid = (B + 3) / 4;

  if (ws_size >= (size_t)WS_TOTAL){
    prep_weights<<<(WS_TOTAL + 255) / 256, 256, 0, stream>>>(
        neW, g1W1, g1W2, g2W1, g2W2, pqW, pkW, ws);
    fused_graphnet<true><<<grid, 256, 0, stream>>>(
        nf, nn_c, neW, neb, g1W1, g1b1, g1W2, g1b2, g2W1, g2b1, g2W2, g2b2,
        n1g, n1b, n2g, n2b, ohW, ohb, c1W, c1b, c2W, c2b, pqW, pqb, pkW, pkb,
        ws, outp, out_size, B);
  } else {
    fused_graphnet<false><<<grid, 256, 0, stream>>>(
        nf, nn_c, neW, neb, g1W1, g1b1, g1W2, g1b2, g2W1, g2b1, g2W2, g2b2,
        n1g, n1b, n2g, n2b, ohW, ohb, c1W, c1b, c2W, c2b, pqW, pqb, pkW, pkb,
        ws, outp, out_size, B);
  }
}

// Round 11
// 916.310 us; speedup vs baseline: 2.5928x; 1.2744x over previous
//
#include <hip/hip_runtime.h>

typedef unsigned char u8;
typedef unsigned int  u32;
using f32x4 = __attribute__((ext_vector_type(4))) float;

#define DI __device__ __forceinline__

// ---- fp8 e4m3 (OCP on gfx950) HW converts ----
DI u32 pk4f8(float a, float b, float c, float d){
  int w = __builtin_amdgcn_cvt_pk_fp8_f32(a, b, 0, false);
  w = __builtin_amdgcn_cvt_pk_fp8_f32(c, d, w, true);
  return (u32)w;
}
DI u8 enc1(float a){
  return (u8)(__builtin_amdgcn_cvt_pk_fp8_f32(a, a, 0, false) & 0xFF);
}
DI float dc0(u32 v){ return __builtin_amdgcn_cvt_f32_fp8((int)v, 0); }
DI float dc1(u32 v){ return __builtin_amdgcn_cvt_f32_fp8((int)v, 1); }
DI float dc2(u32 v){ return __builtin_amdgcn_cvt_f32_fp8((int)v, 2); }
DI float dc3(u32 v){ return __builtin_amdgcn_cvt_f32_fp8((int)v, 3); }

DI f32x4 MFMA8(long a, long b, f32x4 c){
  return __builtin_amdgcn_mfma_f32_16x16x32_fp8_fp8(a, b, c, 0, 0, 0);
}

// fp8 LDS tile: row stride 256 B; XOR swizzle
DI int swz8(int row, int col){ return (row << 8) + (col ^ ((row & 15) << 3)); }
DI long ldsA8(const u8* buf, int row, int k0){ return *(const long*)(buf + swz8(row, k0)); }
DI long ldG8(const u8* p){ return *(const long*)p; }

// fallback builders from f32 global (ws too small); scale ×8 like prep
DI long mk8(float v0, float v1, float v2, float v3, float v4, float v5, float v6, float v7){
  u32 lo = pk4f8(v0, v1, v2, v3), hi = pk4f8(v4, v5, v6, v7);
  return (long)(((unsigned long long)hi << 32) | (unsigned long long)lo);
}
DI long loadW8T(const float* __restrict__ W, int n, int k0){
  return mk8(W[(k0+0)*256+n]*8.f, W[(k0+1)*256+n]*8.f, W[(k0+2)*256+n]*8.f, W[(k0+3)*256+n]*8.f,
             W[(k0+4)*256+n]*8.f, W[(k0+5)*256+n]*8.f, W[(k0+6)*256+n]*8.f, W[(k0+7)*256+n]*8.f);
}
DI long loadW8T16(const float* __restrict__ W, int n, int k0){
  float v[8];
#pragma unroll
  for (int j = 0; j < 8; j++){ int k = k0 + j; v[j] = (k < 16) ? W[k*256+n]*8.f : 0.f; }
  return mk8(v[0],v[1],v[2],v[3],v[4],v[5],v[6],v[7]);
}
DI long loadW8row(const float* __restrict__ W, int n, int k0){
  const float* p = W + n*256 + k0;
  return mk8(p[0]*8.f,p[1]*8.f,p[2]*8.f,p[3]*8.f,p[4]*8.f,p[5]*8.f,p[6]*8.f,p[7]*8.f);
}

// d_ws layout (BYTE offsets), all weights fp8 e4m3, pre-scaled x8
#define WS_NEWT  0        // [256][32]  neW^T, K padded 16->32
#define WS_W1AT1 8192     // [256][256] g1W1[0:256]^T
#define WS_W1BT1 73728    // [256][256] g1W1[256:512]^T
#define WS_W2T1  139264   // [256][256] g1W2^T
#define WS_W1AT2 204800
#define WS_W1BT2 270336
#define WS_W2T2  335872
#define WS_PQWT  401408   // [256][256] pqW^T
#define WS_PKWP  466944   // [256][256] pkW plain copy
#define WS_TOTAL 532480

__global__ void prep_weights(
    const float* __restrict__ neW, const float* __restrict__ g1W1,
    const float* __restrict__ g1W2, const float* __restrict__ g2W1,
    const float* __restrict__ g2W2, const float* __restrict__ pqW,
    const float* __restrict__ pkW, u8* __restrict__ ws)
{
  int i = blockIdx.x * 256 + threadIdx.x;
  if (i >= WS_TOTAL) return;
  float v;
  if (i < 8192){
    int n = i >> 5, k = i & 31;
    v = (k < 16) ? neW[k * 256 + n] : 0.0f;
  } else {
    int j = i - 8192;
    int region = j >> 16;
    int idx = j & 65535;
    int n = idx >> 8, k = idx & 255;
    switch (region){
      case 0: v = g1W1[k * 256 + n]; break;
      case 1: v = g1W1[(256 + k) * 256 + n]; break;
      case 2: v = g1W2[k * 256 + n]; break;
      case 3: v = g2W1[k * 256 + n]; break;
      case 4: v = g2W1[(256 + k) * 256 + n]; break;
      case 5: v = g2W2[k * 256 + n]; break;
      case 6: v = pqW[k * 256 + n]; break;
      default: v = pkW[idx]; break;
    }
  }
  ws[i] = enc1(v * 8.0f);
}

// 1 workgroup = 4 batches = 80 rows. 4 waves; wave owns a 64-col N-slice,
// two sequential 32-col halves; kk loops kept ROLLED (#pragma unroll 1) so the
// scheduler cannot hoist all B-loads and blow the (256,3) register cap.
// Output f32: [oh B*8 | c1 B*10 | c2 B*10 | pl B*20].
template<bool PREPPED>
__global__ __launch_bounds__(256, 3) void fused_graphnet(
    const float* __restrict__ nf, const int* __restrict__ nn_c,
    const float* __restrict__ neW, const float* __restrict__ neb,
    const float* __restrict__ g1W1, const float* __restrict__ g1b1,
    const float* __restrict__ g1W2, const float* __restrict__ g1b2,
    const float* __restrict__ g2W1, const float* __restrict__ g2b1,
    const float* __restrict__ g2W2, const float* __restrict__ g2b2,
    const float* __restrict__ n1g, const float* __restrict__ n1b,
    const float* __restrict__ n2g, const float* __restrict__ n2b,
    const float* __restrict__ ohW, const float* __restrict__ ohb,
    const float* __restrict__ c1W, const float* __restrict__ c1b,
    const float* __restrict__ c2W, const float* __restrict__ c2b,
    const float* __restrict__ pqW, const float* __restrict__ pqb,
    const float* __restrict__ pkW, const float* __restrict__ pkb,
    const u8* __restrict__ ws, float* __restrict__ out,
    int out_n, int Bv)
{
  __shared__ __align__(16) u8 bufA[80 * 256];   // 20KB: h / pre-LN v (fp8)
  __shared__ __align__(16) u8 bufB[80 * 256];   // 20KB: nf then t1 (fp8)
  __shared__ __align__(16) u8 smallA[8 * 256];  // 2KB: msg/g rows 0..3, q rows 4..7
  __shared__ float pbf[4 * 256];                // pb then r (f32)
  __shared__ float rowstats[4][80][2];
  __shared__ float qdot[4];
  __shared__ int   cntS[4];
  __shared__ float dinvS[4];

  const int b0 = blockIdx.x * 4;
  const int tid = threadIdx.x;
  const int wave = tid >> 6, lane = tid & 63;
  const int lg = lane >> 4, lc = lane & 15;
  const int n0 = wave * 64;

  const int Bout = out_n / 48;
  const int off_c1 = 8 * Bout;
  const int off_c2 = 18 * Bout;
  const int off_pl = 28 * Bout;

  if (tid < 4){
    int bi = b0 + tid; if (bi >= Bv) bi = Bv - 1;
    int c = nn_c[bi];
    c = c < 0 ? 0 : (c > 20 ? 20 : c);
    cntS[tid] = c;
    dinvS[tid] = 1.0f / (float)(c < 1 ? 1 : c);
  }

  // zero K-pad cols 16..31 of bufB; stage nf (fp8) into cols 0..15
  for (int i = tid; i < 80 * 4; i += 256){
    int row = i >> 2, c0 = 16 + (i & 3) * 4;
    *(u32*)(bufB + swz8(row, c0)) = 0u;
  }
  for (int i = tid; i < 80 * 4; i += 256){
    int row = i >> 2, k0 = (i & 3) * 4;
    int gr = b0 * 20 + row; if (gr >= Bv * 20) gr = Bv * 20 - 1;
    const float* p = nf + gr * 16 + k0;
    *(u32*)(bufB + swz8(row, k0)) = pk4f8(p[0], p[1], p[2], p[3]);
  }
  __syncthreads();   // S1

  const f32x4 zero4 = {0.0f, 0.0f, 0.0f, 0.0f};

  // GEMM0: h0 = nf @ neW + neb (K=32); two N-halves; A from bufB, h0 -> bufA
#pragma unroll 1
  for (int nh = 0; nh < 2; nh++){
    const int n0h = n0 + nh * 32;
    f32x4 acc[5][2];
#pragma unroll
    for (int mt = 0; mt < 5; mt++){
      long a = ldsA8(bufB, mt * 16 + lc, lg * 8);
#pragma unroll
      for (int nt = 0; nt < 2; nt++){
        int n = n0h + nt * 16 + lc;
        long bfr;
        if constexpr (PREPPED) bfr = ldG8(ws + WS_NEWT + n * 32 + lg * 8);
        else bfr = loadW8T16(neW, n, lg * 8);
        acc[mt][nt] = MFMA8(a, bfr, zero4);
      }
    }
#pragma unroll
    for (int nt = 0; nt < 2; nt++){
      float bb = neb[n0h + nt * 16 + lc];
#pragma unroll
      for (int mt = 0; mt < 5; mt++)
#pragma unroll
        for (int r = 0; r < 4; r++){
          int row = mt * 16 + lg * 4 + r;
          int col = n0h + nt * 16 + lc;
          bufA[swz8(row, col)] = enc1(acc[mt][nt][r] * 0.125f + bb);
        }
    }
  }
  __syncthreads();   // S2

  for (int rd = 0; rd < 2; rd++){
    const int w1at = (rd == 0) ? WS_W1AT1 : WS_W1AT2;
    const int w1bt = (rd == 0) ? WS_W1BT1 : WS_W1BT2;
    const int w2t  = (rd == 0) ? WS_W2T1  : WS_W2T2;
    const float* W1 = (rd == 0) ? g1W1 : g2W1;
    const float* W2 = (rd == 0) ? g1W2 : g2W2;
    const float* b1p = (rd == 0) ? g1b1 : g2b1;
    const float* b2p = (rd == 0) ? g1b2 : g2b2;
    const float* ngp = (rd == 0) ? n1g : n2g;
    const float* nbp = (rd == 0) ? n1b : n2b;

    // masked mean of h (bufA) -> smallA rows 0..3
    {
      int b = tid >> 6;
      int c0 = (tid & 63) * 4;
      int c = cntS[b];
      float s0 = 0, s1 = 0, s2 = 0, s3 = 0;
      for (int r = 0; r < c; r++){
        u32 v = *(const u32*)(bufA + swz8(b * 20 + r, c0));
        s0 += dc0(v); s1 += dc1(v); s2 += dc2(v); s3 += dc3(v);
      }
      float di = dinvS[b];
      *(u32*)(smallA + swz8(b, c0)) = pk4f8(s0 * di, s1 * di, s2 * di, s3 * di);
    }
    __syncthreads();   // S3

    // pb = msg @ W1b + b1 -> pbf (lg==0, own cols); two N-halves
#pragma unroll 1
    for (int nh = 0; nh < 2; nh++){
      const int n0h = n0 + nh * 32;
      f32x4 acc[2];
#pragma unroll
      for (int nt = 0; nt < 2; nt++) acc[nt] = zero4;
#pragma unroll 1
      for (int kk = 0; kk < 8; kk++){
        long a = ldsA8(smallA, lc & 3, kk * 32 + lg * 8);
#pragma unroll
        for (int nt = 0; nt < 2; nt++){
          int n = n0h + nt * 16 + lc;
          long bfr;
          if constexpr (PREPPED) bfr = ldG8(ws + w1bt + n * 256 + kk * 32 + lg * 8);
          else bfr = loadW8T(W1 + 256 * 256, n, kk * 32 + lg * 8);
          acc[nt] = MFMA8(a, bfr, acc[nt]);
        }
      }
      if (lg == 0){
#pragma unroll
        for (int nt = 0; nt < 2; nt++)
#pragma unroll
          for (int r = 0; r < 4; r++){
            int col = n0h + nt * 16 + lc;
            pbf[r * 256 + col] = acc[nt][r] * 0.125f + b1p[col];
          }
      }
    }

    // G1: t1 = relu(h @ W1a * 0.125 + pb) -> bufB; two N-halves
#pragma unroll 1
    for (int nh = 0; nh < 2; nh++){
      const int n0h = n0 + nh * 32;
      f32x4 tacc[5][2];
#pragma unroll
      for (int mt = 0; mt < 5; mt++)
#pragma unroll
        for (int nt = 0; nt < 2; nt++) tacc[mt][nt] = zero4;
#pragma unroll 1
      for (int kk = 0; kk < 8; kk++){
#pragma unroll
        for (int mt = 0; mt < 5; mt++){
          long a = ldsA8(bufA, mt * 16 + lc, kk * 32 + lg * 8);
#pragma unroll
          for (int nt = 0; nt < 2; nt++){
            int n = n0h + nt * 16 + lc;
            long bfr;
            if constexpr (PREPPED) bfr = ldG8(ws + w1at + n * 256 + kk * 32 + lg * 8);
            else bfr = loadW8T(W1, n, kk * 32 + lg * 8);
            tacc[mt][nt] = MFMA8(a, bfr, tacc[mt][nt]);
          }
        }
      }
#pragma unroll
      for (int mt = 0; mt < 5; mt++)
#pragma unroll
        for (int nt = 0; nt < 2; nt++)
#pragma unroll
          for (int r = 0; r < 4; r++){
            int row = mt * 16 + lg * 4 + r;
            int col = n0h + nt * 16 + lc;
            float v = tacc[mt][nt][r] * 0.125f + pbf[(row / 20) * 256 + col];
            bufB[swz8(row, col)] = enc1(fmaxf(v, 0.0f));
          }
    }
    __syncthreads();   // S4: t1 visible; all G1 h-reads done

    // G2: v = t1 @ W2 * 0.125 + residual(bufA) + b2 -> bufA (own cols, pre-LN)
#pragma unroll 1
    for (int nh = 0; nh < 2; nh++){
      const int n0h = n0 + nh * 32;
      f32x4 tacc[5][2];
#pragma unroll
      for (int mt = 0; mt < 5; mt++)
#pragma unroll
        for (int nt = 0; nt < 2; nt++) tacc[mt][nt] = zero4;
#pragma unroll 1
      for (int kk = 0; kk < 8; kk++){
#pragma unroll
        for (int mt = 0; mt < 5; mt++){
          long a = ldsA8(bufB, mt * 16 + lc, kk * 32 + lg * 8);
#pragma unroll
          for (int nt = 0; nt < 2; nt++){
            int n = n0h + nt * 16 + lc;
            long bfr;
            if constexpr (PREPPED) bfr = ldG8(ws + w2t + n * 256 + kk * 32 + lg * 8);
            else bfr = loadW8T(W2, n, kk * 32 + lg * 8);
            tacc[mt][nt] = MFMA8(a, bfr, tacc[mt][nt]);
          }
        }
      }
#pragma unroll
      for (int nt = 0; nt < 2; nt++){
        float b2s = b2p[n0h + nt * 16 + lc];
#pragma unroll
        for (int mt = 0; mt < 5; mt++)
#pragma unroll
          for (int r = 0; r < 4; r++){
            int row = mt * 16 + lg * 4 + r;
            int col = n0h + nt * 16 + lc;
            u32 rv = bufA[swz8(row, col)];              // residual (same thread wrote it)
            float v = tacc[mt][nt][r] * 0.125f + dc0(rv) + b2s;
            bufA[swz8(row, col)] = enc1(v);             // pre-LN v, own cols
          }
      }
    }

    // LN: stats from bufA (own cols, same-thread RAW -> no barrier needed yet)
    {
#pragma unroll
      for (int mt = 0; mt < 5; mt++)
#pragma unroll
        for (int r = 0; r < 4; r++){
          int row = mt * 16 + lg * 4 + r;
          float s1 = 0, s2 = 0;
#pragma unroll
          for (int nt = 0; nt < 4; nt++){
            float v = dc0((u32)bufA[swz8(row, n0 + nt * 16 + lc)]);
            s1 += v; s2 += v * v;
          }
#pragma unroll
          for (int d = 1; d < 16; d <<= 1){ s1 += __shfl_xor(s1, d, 64); s2 += __shfl_xor(s2, d, 64); }
          if (lc == 0){ rowstats[wave][row][0] = s1; rowstats[wave][row][1] = s2; }
        }
      __syncthreads();   // S5

      float ngv[4], nbv[4];
#pragma unroll
      for (int nt = 0; nt < 4; nt++){
        ngv[nt] = ngp[n0 + nt * 16 + lc];
        nbv[nt] = nbp[n0 + nt * 16 + lc];
      }
#pragma unroll
      for (int mt = 0; mt < 5; mt++)
#pragma unroll
        for (int r = 0; r < 4; r++){
          int row = mt * 16 + lg * 4 + r;
          float t1s = rowstats[0][row][0] + rowstats[1][row][0] + rowstats[2][row][0] + rowstats[3][row][0];
          float t2s = rowstats[0][row][1] + rowstats[1][row][1] + rowstats[2][row][1] + rowstats[3][row][1];
          float mean = t1s * (1.0f / 256.0f);
          float var  = t2s * (1.0f / 256.0f) - mean * mean;
          float rstd = rsqrtf(fmaxf(var, 0.0f) + 1e-5f);
          int bb = row / 20;
          float mf = ((row - bb * 20) < cntS[bb]) ? 1.0f : 0.0f;
#pragma unroll
          for (int nt = 0; nt < 4; nt++){
            int col = n0 + nt * 16 + lc;
            float v = dc0((u32)bufA[swz8(row, col)]);
            bufA[swz8(row, col)] = enc1(((v - mean) * rstd * ngv[nt] + nbv[nt]) * mf);
          }
        }
    }
    __syncthreads();   // S6
  }

  // g = masked mean -> smallA rows 0..3
  {
    int b = tid >> 6;
    int c0 = (tid & 63) * 4;
    int c = cntS[b];
    float s0 = 0, s1 = 0, s2 = 0, s3 = 0;
    for (int r = 0; r < c; r++){
      u32 v = *(const u32*)(bufA + swz8(b * 20 + r, c0));
      s0 += dc0(v); s1 += dc1(v); s2 += dc2(v); s3 += dc3(v);
    }
    float di = dinvS[b];
    *(u32*)(smallA + swz8(b, c0)) = pk4f8(s0 * di, s1 * di, s2 * di, s3 * di);
  }
  __syncthreads();   // S7

  // q = g @ pqW + pqb -> smallA rows 4..7
  {
    f32x4 qacc[4];
#pragma unroll
    for (int nt = 0; nt < 4; nt++) qacc[nt] = zero4;
#pragma unroll 1
    for (int kk = 0; kk < 8; kk++){
      long a = ldsA8(smallA, lc & 3, kk * 32 + lg * 8);
#pragma unroll
      for (int nt = 0; nt < 4; nt++){
        int n = n0 + nt * 16 + lc;
        long bfr;
        if constexpr (PREPPED) bfr = ldG8(ws + WS_PQWT + n * 256 + kk * 32 + lg * 8);
        else bfr = loadW8T(pqW, n, kk * 32 + lg * 8);
        qacc[nt] = MFMA8(a, bfr, qacc[nt]);
      }
    }
    if (lg == 0){
#pragma unroll
      for (int nt = 0; nt < 4; nt++)
#pragma unroll
        for (int r = 0; r < 4; r++){
          int col = n0 + nt * 16 + lc;
          smallA[swz8(4 + r, col)] = enc1(qacc[nt][r] * 0.125f + pqb[col]);
        }
    }
  }
  __syncthreads();   // S8

  // qdot[b] = q[b].pkb (wave w = batch w)
  {
    u32 qv = *(const u32*)(smallA + swz8(4 + wave, lane * 4));
    float p = dc0(qv) * pkb[lane * 4 + 0] + dc1(qv) * pkb[lane * 4 + 1]
            + dc2(qv) * pkb[lane * 4 + 2] + dc3(qv) * pkb[lane * 4 + 3];
#pragma unroll
    for (int d = 1; d < 64; d <<= 1) p += __shfl_xor(p, d, 64);
    if (lane == 0) qdot[wave] = p;
  }

  // r[b][n] = sum_k q[b][k]*pkW[n][k] -> pbf
  {
    f32x4 racc[4];
#pragma unroll
    for (int nt = 0; nt < 4; nt++) racc[nt] = zero4;
#pragma unroll 1
    for (int kk = 0; kk < 8; kk++){
      long a = ldsA8(smallA, 4 + (lc & 3), kk * 32 + lg * 8);
#pragma unroll
      for (int nt = 0; nt < 4; nt++){
        int n = n0 + nt * 16 + lc;
        long bfr;
        if constexpr (PREPPED) bfr = ldG8(ws + WS_PKWP + n * 256 + kk * 32 + lg * 8);
        else bfr = loadW8row(pkW, n, kk * 32 + lg * 8);
        racc[nt] = MFMA8(a, bfr, racc[nt]);
      }
    }
    if (lg == 0){
#pragma unroll
      for (int nt = 0; nt < 4; nt++)
#pragma unroll
        for (int r = 0; r < 4; r++)
          pbf[r * 256 + (n0 + nt * 16 + lc)] = racc[nt][r] * 0.125f;
    }
  }
  __syncthreads();   // S9

  // pl[b,n] = h[row].r[b] + qdot[b] (masked -> exactly -1e9)
  {
    const int b = wave;
    if (b0 + b < Bv){
      int cb = cntS[b];
      float qd = qdot[b];
      for (int rr = 0; rr < 20; rr++){
        int row = b * 20 + rr;
        u32 hv = *(const u32*)(bufA + swz8(row, lane * 4));
        const float* rp = pbf + b * 256 + lane * 4;
        float p = dc0(hv) * rp[0] + dc1(hv) * rp[1] + dc2(hv) * rp[2] + dc3(hv) * rp[3];
#pragma unroll
        for (int d = 1; d < 64; d <<= 1) p += __shfl_xor(p, d, 64);
        if (lane == 0){
          float v = (rr < cb) ? (p + qd) : -1e9f;
          out[off_pl + (b0 + b) * 20 + rr] = v;
        }
      }
    }
  }

  // heads (wave w = batch w): oh [B,8]@0, c1 [B,10]@off_c1, c2 [B,10]@off_c2
  {
    const int b = wave;
    if (b0 + b < Bv){
      u32 gv = *(const u32*)(smallA + swz8(b, lane * 4));
      float g0 = dc0(gv), g1 = dc1(gv), g2 = dc2(gv), g3 = dc3(gv);
#pragma unroll 1
      for (int o = 0; o < 28; o++){
        const float* W; const float* bias; int ncol, col, off;
        if (o < 8)      { W = ohW; bias = ohb; ncol = 8;  col = o;      off = 0; }
        else if (o < 18){ W = c1W; bias = c1b; ncol = 10; col = o - 8;  off = off_c1; }
        else            { W = c2W; bias = c2b; ncol = 10; col = o - 18; off = off_c2; }
        int k = lane * 4;
        float p = g0 * W[(k + 0) * ncol + col] + g1 * W[(k + 1) * ncol + col]
                + g2 * W[(k + 2) * ncol + col] + g3 * W[(k + 3) * ncol + col];
#pragma unroll
        for (int d = 1; d < 64; d <<= 1) p += __shfl_xor(p, d, 64);
        if (lane == 0) out[off + (b0 + b) * ncol + col] = p + bias[col];
      }
    }
  }
}

extern "C" void kernel_launch(void* const* d_in, const int* in_sizes, int n_in,
                              void* d_out, int out_size, void* d_ws, size_t ws_size,
                              hipStream_t stream)
{
  const float* nf   = (const float*)d_in[0];
  const int*   nn_c = (const int*)d_in[1];
  const float* neW  = (const float*)d_in[2];
  const float* neb  = (const float*)d_in[3];
  const float* g1W1 = (const float*)d_in[4];
  const float* g1b1 = (const float*)d_in[5];
  const float* g1W2 = (const float*)d_in[6];
  const float* g1b2 = (const float*)d_in[7];
  const float* g2W1 = (const float*)d_in[8];
  const float* g2b1 = (const float*)d_in[9];
  const float* g2W2 = (const float*)d_in[10];
  const float* g2b2 = (const float*)d_in[11];
  const float* n1g  = (const float*)d_in[12];
  const float* n1b  = (const float*)d_in[13];
  const float* n2g  = (const float*)d_in[14];
  const float* n2b  = (const float*)d_in[15];
  const float* ohW  = (const float*)d_in[16];
  const float* ohb  = (const float*)d_in[17];
  const float* c1W  = (const float*)d_in[18];
  const float* c1b  = (const float*)d_in[19];
  const float* c2W  = (const float*)d_in[20];
  const float* c2b  = (const float*)d_in[21];
  const float* pqW  = (const float*)d_in[22];
  const float* pqb  = (const float*)d_in[23];
  const float* pkW  = (const float*)d_in[24];
  const float* pkb  = (const float*)d_in[25];

  float* outp = (float*)d_out;
  u8* ws = (u8*)d_ws;
  int B = in_sizes[0] / 320;       // nf is [B,20,16]
  int grid = (B + 3) / 4;

  if (ws_size >= (size_t)WS_TOTAL){
    prep_weights<<<(WS_TOTAL + 255) / 256, 256, 0, stream>>>(
        neW, g1W1, g1W2, g2W1, g2W2, pqW, pkW, ws);
    fused_graphnet<true><<<grid, 256, 0, stream>>>(
        nf, nn_c, neW, neb, g1W1, g1b1, g1W2, g1b2, g2W1, g2b1, g2W2, g2b2,
        n1g, n1b, n2g, n2b, ohW, ohb, c1W, c1b, c2W, c2b, pqW, pqb, pkW, pkb,
        ws, outp, out_size, B);
  } else {
    fused_graphnet<false><<<grid, 256, 0, stream>>>(
        nf, nn_c, neW, neb, g1W1, g1b1, g1W2, g1b2, g2W1, g2b1, g2W2, g2b2,
        n1g, n1b, n2g, n2b, ohW, ohb, c1W, c1b, c2W, c2b, pqW, pqb, pkW, pkb,
        ws, outp, out_size, B);
  }
}